// Round 9
// baseline (435.843 us; speedup 1.0000x reference)
//
#include <hip/hip_runtime.h>

#define S_LEN 920
#define DMODEL 1536
#define NH 4
#define HD 384
#define LREL 1839
#define BATCH 8
#define MTOT (BATCH * S_LEN)   // 7360
#define KPAD 960               // padded key-dim (Vt cols)
#define NBH (BATCH * NH)       // 32

// ---- Q/K live inside d_out (shorts). Per 2-batch pair p, shorts
// [p*CHS, (p+1)*CHS) hold [Q(2p),K(2p),Q(2p+1),K(2p+1)].  The fused kernel for
// half h reads batches 4h..4h+3; its O goes to scratch; k_copy_o then writes
// d_out, overwriting exactly those batches' Q/K slabs (all reads done).
#define CHS   5652480UL        // pair stride in shorts
#define BSLAB 2826240UL        // per-batch Q+K slab in shorts
#define KOFF  1413120UL        // K offset within batch slab (shorts)

#define EB_BYTES 1412352UL
#define VT_BYTES 23592960UL

typedef __attribute__((ext_vector_type(8))) short  s16x8;
typedef __attribute__((ext_vector_type(4))) short  s16x4;
typedef __attribute__((ext_vector_type(8))) __bf16 bf16x8;
typedef __attribute__((ext_vector_type(4))) float  f32x4;

__device__ __forceinline__ short f2b(float x) {
  unsigned u = __builtin_bit_cast(unsigned, x);
  unsigned r = (u + 0x7FFFu + ((u >> 16) & 1u)) >> 16;
  return (short)r;
}
__device__ __forceinline__ float b2f(short s) {
  unsigned u = ((unsigned)(unsigned short)s) << 16;
  return __builtin_bit_cast(float, u);
}

__device__ __forceinline__ void load_lds16(const short* g, short* lds) {
  __builtin_amdgcn_global_load_lds(
      (const __attribute__((address_space(1))) void*)g,
      (__attribute__((address_space(3))) void*)lds, 16, 0, 0);
}

__device__ __forceinline__ f32x4 mfma_bf16(s16x8 a, s16x8 b, f32x4 c) {
  return __builtin_amdgcn_mfma_f32_16x16x32_bf16(
      __builtin_bit_cast(bf16x8, a), __builtin_bit_cast(bf16x8, b), c, 0, 0, 0);
}

// swizzled ds_read of one MFMA fragment (row stride 128 B, XOR 16B-slot).
__device__ __forceinline__ s16x8 frag_swz(const short* base, int row, int kk, int lq) {
  int byte = (row << 7) + (kk << 6) + (lq << 4);
  byte ^= (row & 7) << 4;
  return *(const s16x8*)((const char*)base + byte);
}

// ---------------------------------------------------------------------------
// Pipelined 256x192 GEMM core (qkv) — proven.
// ---------------------------------------------------------------------------
template <int NT>
__device__ __forceinline__ void gemm_pipe(short* smem,
    const short* __restrict__ A, int ldA, int mClamp, int m0,
    const short* __restrict__ B, int ldB, int nClamp, int n0,
    f32x4 acc[4][6]) {
  short* const A0 = smem;
  short* const B0 = smem + 16384;
  short* const A1 = smem + 28672;
  short* const B1 = smem + 45056;

  const int tid = threadIdx.x, w = tid >> 6, lane = tid & 63;
  const int lr = lane & 15, lq = lane >> 4;
  const int wr = w >> 1, wc = w & 1;

  const short* pa[4]; int la[4];
  const short* pb[3]; int lb[3];
  {
    const int rl = lane >> 3, c = lane & 7;
#pragma unroll
    for (int i = 0; i < 4; ++i) {
      int r = w * 32 + i * 8 + rl;
      int ra = m0 + r; if (ra > mClamp) ra = mClamp;
      pa[i] = A + (size_t)ra * ldA + ((c ^ (r & 7)) * 8);
      la[i] = (w * 32 + i * 8) * 64;
    }
#pragma unroll
    for (int i = 0; i < 3; ++i) {
      int r = w * 24 + i * 8 + rl;
      int rb = n0 + r; if (rb > nClamp) rb = nClamp;
      pb[i] = B + (size_t)rb * ldB + ((c ^ (r & 7)) * 8);
      lb[i] = (w * 24 + i * 8) * 64;
    }
  }

#pragma unroll
  for (int i = 0; i < 4; ++i)
#pragma unroll
    for (int j = 0; j < 6; ++j) acc[i][j] = (f32x4){0.f, 0.f, 0.f, 0.f};

#pragma unroll
  for (int i = 0; i < 4; ++i) load_lds16(pa[i], A0 + la[i]);
#pragma unroll
  for (int i = 0; i < 3; ++i) load_lds16(pb[i], B0 + lb[i]);

  for (int kt = 0; kt < NT; ++kt) {
    short* const Ab = (kt & 1) ? A1 : A0;
    short* const Bb = (kt & 1) ? B1 : B0;
    short* const An = (kt & 1) ? A0 : A1;
    short* const Bn = (kt & 1) ? B0 : B1;

    if (kt + 1 < NT) {
      const int k0 = (kt + 1) * 64;
#pragma unroll
      for (int i = 0; i < 4; ++i) load_lds16(pa[i] + k0, An + la[i]);
#pragma unroll
      for (int i = 0; i < 3; ++i) load_lds16(pb[i] + k0, Bn + lb[i]);
      asm volatile("s_waitcnt vmcnt(7)" ::: "memory");
    } else {
      asm volatile("s_waitcnt vmcnt(0)" ::: "memory");
    }
    __builtin_amdgcn_sched_barrier(0);
    __builtin_amdgcn_s_barrier();
    __builtin_amdgcn_sched_barrier(0);

    s16x8 a[4], bb[3];
#pragma unroll
    for (int f = 0; f < 4; ++f) a[f] = frag_swz(Ab, wr * 64 + f * 16 + lr, 0, lq);
#pragma unroll
    for (int f = 0; f < 3; ++f) bb[f] = frag_swz(Bb, wc * 96 + f * 16 + lr, 0, lq);
    __builtin_amdgcn_s_barrier();
    __builtin_amdgcn_s_setprio(1);
#pragma unroll
    for (int i = 0; i < 4; ++i)
#pragma unroll
      for (int j = 0; j < 3; ++j) acc[i][j] = mfma_bf16(a[i], bb[j], acc[i][j]);
    __builtin_amdgcn_s_setprio(0);
    __builtin_amdgcn_s_barrier();
#pragma unroll
    for (int f = 0; f < 3; ++f) bb[f] = frag_swz(Bb, wc * 96 + (3 + f) * 16 + lr, 0, lq);
    __builtin_amdgcn_s_barrier();
    __builtin_amdgcn_s_setprio(1);
#pragma unroll
    for (int i = 0; i < 4; ++i)
#pragma unroll
      for (int j = 0; j < 3; ++j) acc[i][3 + j] = mfma_bf16(a[i], bb[j], acc[i][3 + j]);
    __builtin_amdgcn_s_setprio(0);
    __builtin_amdgcn_s_barrier();
#pragma unroll
    for (int f = 0; f < 4; ++f) a[f] = frag_swz(Ab, wr * 64 + f * 16 + lr, 1, lq);
#pragma unroll
    for (int f = 0; f < 3; ++f) bb[f] = frag_swz(Bb, wc * 96 + f * 16 + lr, 1, lq);
    __builtin_amdgcn_s_barrier();
    __builtin_amdgcn_s_setprio(1);
#pragma unroll
    for (int i = 0; i < 4; ++i)
#pragma unroll
      for (int j = 0; j < 3; ++j) acc[i][j] = mfma_bf16(a[i], bb[j], acc[i][j]);
    __builtin_amdgcn_s_setprio(0);
    __builtin_amdgcn_s_barrier();
#pragma unroll
    for (int f = 0; f < 3; ++f) bb[f] = frag_swz(Bb, wc * 96 + (3 + f) * 16 + lr, 1, lq);
    __builtin_amdgcn_s_barrier();
    __builtin_amdgcn_s_setprio(1);
#pragma unroll
    for (int i = 0; i < 4; ++i)
#pragma unroll
      for (int j = 0; j < 3; ++j) acc[i][3 + j] = mfma_bf16(a[i], bb[j], acc[i][3 + j]);
    __builtin_amdgcn_s_setprio(0);
    __builtin_amdgcn_s_barrier();
  }
}

// ---------------------------------------------------------------------------
__global__ void k_cast(const float* __restrict__ X, short* __restrict__ O, int n4) {
  int i = blockIdx.x * blockDim.x + threadIdx.x;
  if (i >= n4) return;
  float4 v = ((const float4*)X)[i];
  s16x4 o = {f2b(v.x), f2b(v.y), f2b(v.z), f2b(v.w)};
  *(s16x4*)&O[(size_t)i * 4] = o;
}

// merged: cast distance_embedding -> Eb  AND  zero Vt pad columns (disjoint).
#define EB_N4   (LREL * HD / 4)                   // 176544
#define PAD_N   (NBH * HD * (KPAD - S_LEN))       // 491520
__global__ void k_prep_ev(const float* __restrict__ de, short* __restrict__ Eb,
                          short* __restrict__ Vt) {
  int i = blockIdx.x * blockDim.x + threadIdx.x;
  if (i < EB_N4) {
    float4 v = ((const float4*)de)[i];
    s16x4 o = {f2b(v.x), f2b(v.y), f2b(v.z), f2b(v.w)};
    *(s16x4*)&Eb[(size_t)i * 4] = o;
  } else {
    int idx = i - EB_N4;
    if (idx < PAD_N) {
      int bhd = idx / (KPAD - S_LEN);
      int s = S_LEN + idx - bhd * (KPAD - S_LEN);
      Vt[(size_t)bhd * KPAD + s] = 0;
    }
  }
}

__global__ void k_transpose_w(const float* __restrict__ W0, const float* __restrict__ W1,
                              const float* __restrict__ W2, short* __restrict__ Wt) {
  const float* W = (blockIdx.z == 0) ? W0 : ((blockIdx.z == 1) ? W1 : W2);
  short* O = Wt + (size_t)blockIdx.z * DMODEL * DMODEL;
  __shared__ float t[32][33];
  int tx = threadIdx.x, ty = threadIdx.y;
  int n0 = blockIdx.x * 32, k0 = blockIdx.y * 32;
#pragma unroll
  for (int i = 0; i < 4; ++i)
    t[ty + i * 8][tx] = W[(size_t)(k0 + ty + i * 8) * DMODEL + n0 + tx];
  __syncthreads();
#pragma unroll
  for (int i = 0; i < 4; ++i)
    O[(size_t)(n0 + ty + i * 8) * DMODEL + k0 + tx] = f2b(t[tx][ty + i * 8]);
}

// ---------------------------------------------------------------------------
// QKV: 256x192 tile pipeline.  Grid (232,1,3), 1 block/CU.
// Block mapping: n_idx = t&7, m_idx = t>>3.  With round-robin blockIdx->XCD
// (and z-stride 232 % 8 == 0), each XCD sees exactly ONE 192-col weight panel
// per z (576 KB, L2-resident for the whole m-sweep); the A-tile streams from
// L3 (Xb fully L3-resident).  Round-1's chunked swizzle cycled all 8 panels
// through each XCD (~23 MB working set vs 4 MB L2) -> 115 MB HBM overfetch.
// ---------------------------------------------------------------------------
#define QKV_NT (DMODEL / 64)   // 24 K-tiles

__global__ __launch_bounds__(512, 2) void k_gemm_qkv(const short* __restrict__ Xb,
                                                     const short* __restrict__ Wt,
                                                     short* __restrict__ out16,
                                                     short* __restrict__ Vt) {
  __shared__ short smem[57344];
  const int z = blockIdx.z;
  const int t = blockIdx.x;
  const int m0 = (t >> 3) * 256;                // [0,29) m-tiles
  const int n0 = (t & 7) * 192;                 // n-panel pinned per XCD

  const int tid = threadIdx.x, w = tid >> 6, lane = tid & 63;
  const int lr = lane & 15, lq = lane >> 4;
  const int wr = w >> 1, wc = w & 1;

  f32x4 acc[4][6];
  gemm_pipe<QKV_NT>(smem, Xb, DMODEL, MTOT - 1, m0,
                    Wt + (size_t)z * DMODEL * DMODEL, DMODEL, DMODEL - 1, n0, acc);

  __syncthreads();
  const float inv = 0.05103103630798287f;       // 1/sqrt(384)
  if (z != 2) {
    short* T = smem;                            // [256][200]
#pragma unroll
    for (int i = 0; i < 4; ++i)
#pragma unroll
      for (int j = 0; j < 6; ++j) {
        int ml = wr * 64 + i * 16 + lq * 4;
        int nl = wc * 96 + j * 16 + lr;
#pragma unroll
        for (int r = 0; r < 4; ++r) {
          float v = acc[i][j][r];
          T[(ml + r) * 200 + nl] = f2b(z == 0 ? v * inv : v);
        }
      }
    __syncthreads();
    for (int u = 0; u < 12; ++u) {
      int unit = u * 512 + tid;
      int ml = unit / 24, c = unit - ml * 24;
      int m = m0 + ml;
      if (m < MTOT) {
        int b = m / S_LEN, s = m - b * S_LEN;
        short* dst = out16 + (size_t)(b >> 1) * CHS + (size_t)(b & 1) * BSLAB +
                     (z == 1 ? KOFF : 0UL) + (size_t)s * DMODEL + n0 + c * 8;
        *(s16x8*)dst = *(const s16x8*)&T[ml * 200 + c * 8];
      }
    }
  } else {
    short* T = smem;                            // [192][264] transposed
#pragma unroll
    for (int i = 0; i < 4; ++i)
#pragma unroll
      for (int j = 0; j < 6; ++j) {
        int ml = wr * 64 + i * 16 + lq * 4;
        int nl = wc * 96 + j * 16 + lr;
#pragma unroll
        for (int r = 0; r < 4; ++r)
          T[nl * 264 + ml + r] = f2b(acc[i][j][r]);
      }
    __syncthreads();
    const int h = n0 / HD;
    const int d0 = n0 - h * HD;
    for (int u = 0; u < 12; ++u) {
      int unit = u * 512 + tid;
      int nl = unit >> 5, c = unit & 31;
      int m = m0 + c * 8;
      if (m < MTOT) {
        int b = m / S_LEN, s = m - b * S_LEN;
        size_t row = (size_t)(b * NH + h) * HD + d0 + nl;
        *(s16x8*)&Vt[row * KPAD + s] = *(const s16x8*)&T[nl * 264 + c * 8];
      }
    }
  }
}

// ---------------------------------------------------------------------------
// FUSED attention v1 (round-3, best measured): per block one bh x 64 q-rows.
// 5 KV-tiles of 192 keys.  Per tile: 6 E-slots (T=Q*E^T -> TL bf16), 6 K-slots
// (S=Q*K^T), online softmax (P -> PL aliasing TL), 6 V-slots (O += P*V).
// Counted-vmcnt ring, swizzled LDS, setprio MFMA clusters.
// ---------------------------------------------------------------------------
#define FKV 192
#define FNT 5

#define WAITVM(N) { asm volatile("s_waitcnt vmcnt(" #N ")" ::: "memory"); \
  __builtin_amdgcn_sched_barrier(0); __builtin_amdgcn_s_barrier(); \
  __builtin_amdgcn_sched_barrier(0); }

#define LBAR { asm volatile("s_waitcnt lgkmcnt(0)" ::: "memory"); \
  __builtin_amdgcn_sched_barrier(0); __builtin_amdgcn_s_barrier(); \
  __builtin_amdgcn_sched_barrier(0); }

#define NOISSUE { }

#define STAGE_E(BUF, C, L0) { \
  _Pragma("unroll") for (int i_ = 0; i_ < 4; ++i_) { \
    int r_ = w * 32 + i_ * 8 + rl; \
    int rg_ = (L0) + r_; rg_ = rg_ < 0 ? 0 : (rg_ > LREL - 1 ? LREL - 1 : rg_); \
    load_lds16(Eb + (size_t)rg_ * HD + ((cs ^ (r_ & 7)) * 8) + (C) * 64, \
               (BUF) + (w * 32 + i_ * 8) * 64); } }

#define STAGE_K(BUF, C) { \
  _Pragma("unroll") for (int i_ = 0; i_ < 3; ++i_) { \
    int r_ = w * 24 + i_ * 8 + rl; \
    int rg_ = kv0 + r_; if (rg_ > S_LEN - 1) rg_ = S_LEN - 1; \
    load_lds16(Kp + (size_t)rg_ * DMODEL + ((cs ^ (r_ & 7)) * 8) + (C) * 64, \
               (BUF) + (w * 24 + i_ * 8) * 64); } }

#define STAGE_V(BUF, HF, SC) { \
  _Pragma("unroll") for (int i_ = 0; i_ < 3; ++i_) { \
    int r_ = w * 24 + i_ * 8 + rl; \
    load_lds16(Vb + (size_t)((HF) * 192 + r_) * KPAD + kv0 + (SC) * 64 + ((cs ^ (r_ & 7)) * 8), \
               (BUF) + (w * 24 + i_ * 8) * 64); } }

#define GSLOT_T(CUR, C, ISSUE, WVM) { ISSUE; WVM; \
  s16x8 a_[2][2], b_[2][4]; \
  _Pragma("unroll") for (int k_ = 0; k_ < 2; ++k_) { \
    _Pragma("unroll") for (int i_ = 0; i_ < 2; ++i_) \
      a_[i_][k_] = frag_swz(QL + (C) * 4096, wm * 32 + i_ * 16 + lr, k_, lq); \
    _Pragma("unroll") for (int j_ = 0; j_ < 4; ++j_) \
      b_[k_][j_] = frag_swz((CUR), wn * 64 + j_ * 16 + lr, k_, lq); } \
  __builtin_amdgcn_s_setprio(1); \
  _Pragma("unroll") for (int k_ = 0; k_ < 2; ++k_) \
    _Pragma("unroll") for (int i_ = 0; i_ < 2; ++i_) \
      _Pragma("unroll") for (int j_ = 0; j_ < 4; ++j_) \
        acc_t[i_][j_] = mfma_bf16(a_[i_][k_], b_[k_][j_], acc_t[i_][j_]); \
  __builtin_amdgcn_s_setprio(0); __builtin_amdgcn_s_barrier(); }

#define GSLOT_S(CUR, C, ISSUE, WVM) { ISSUE; WVM; \
  s16x8 a_[2][2], b_[2][3]; \
  _Pragma("unroll") for (int k_ = 0; k_ < 2; ++k_) { \
    _Pragma("unroll") for (int i_ = 0; i_ < 2; ++i_) \
      a_[i_][k_] = frag_swz(QL + (C) * 4096, wm * 32 + i_ * 16 + lr, k_, lq); \
    _Pragma("unroll") for (int j_ = 0; j_ < 3; ++j_) \
      b_[k_][j_] = frag_swz((CUR), wn * 48 + j_ * 16 + lr, k_, lq); } \
  __builtin_amdgcn_s_setprio(1); \
  _Pragma("unroll") for (int k_ = 0; k_ < 2; ++k_) \
    _Pragma("unroll") for (int i_ = 0; i_ < 2; ++i_) \
      _Pragma("unroll") for (int j_ = 0; j_ < 3; ++j_) \
        acc_s[i_][j_] = mfma_bf16(a_[i_][k_], b_[k_][j_], acc_s[i_][j_]); \
  __builtin_amdgcn_s_setprio(0); __builtin_amdgcn_s_barrier(); }

#define GSLOT_PV(CUR, SC, HF, ISSUE, WVM) { ISSUE; WVM; \
  s16x8 a_[2][2], b_[2][3]; \
  _Pragma("unroll") for (int k_ = 0; k_ < 2; ++k_) { \
    _Pragma("unroll") for (int i_ = 0; i_ < 2; ++i_) \
      a_[i_][k_] = frag_swz(TLP + (SC) * 4096, wm * 32 + i_ * 16 + lr, k_, lq); \
    _Pragma("unroll") for (int j_ = 0; j_ < 3; ++j_) \
      b_[k_][j_] = frag_swz((CUR), wn * 48 + j_ * 16 + lr, k_, lq); } \
  __builtin_amdgcn_s_setprio(1); \
  _Pragma("unroll") for (int k_ = 0; k_ < 2; ++k_) \
    _Pragma("unroll") for (int i_ = 0; i_ < 2; ++i_) \
      _Pragma("unroll") for (int j_ = 0; j_ < 3; ++j_) \
        acc_o[i_][(HF) * 3 + j_] = mfma_bf16(a_[i_][k_], b_[k_][j_], acc_o[i_][(HF) * 3 + j_]); \
  __builtin_amdgcn_s_setprio(0); __builtin_amdgcn_s_barrier(); }

__global__ __launch_bounds__(512, 1) void k_fused(const short* __restrict__ out16,
                                                  const short* __restrict__ Vt,
                                                  const short* __restrict__ Eb,
                                                  float* __restrict__ O, int half) {
  __shared__ short smem[74752];          // 149.5 KB
  short* const QL  = smem;               // 6 chunks [64][64]   (24576)
  short* const B0  = smem + 24576;       // [256][64]           (16384)
  short* const B1  = smem + 40960;       // [256][64]           (16384)
  short* const TLP = smem + 57344;       // TL [64][256] / PL 3x[64][64] (16384)
  float* const pmax = (float*)(smem + 73728);   // [4][64]
  float* const psum = pmax + 256;               // [4][64]

  const int f  = blockIdx.x;             // [0,240)
  const int f2 = (f & 7) * 30 + (f >> 3);
  const int mt = f2 % 15, bhl = f2 / 15;
  const int bh = half * 16 + bhl, b = bh >> 2, h = bh & 3;
  const int m0 = mt * 64;

  const int tid = threadIdx.x, w = tid >> 6, lane = tid & 63;
  const int lr = lane & 15, lq = lane >> 4;
  const int wm = w >> 2, wn = w & 3;     // 2m x 4n waves; wave = 32 rows x 48 cols
  const int rl = lane >> 3, cs = lane & 7;

  const short* Qp = out16 + (size_t)(b >> 1) * CHS + (size_t)(b & 1) * BSLAB + h * HD;
  const short* Kp = Qp + KOFF;
  const short* Vb = Vt + (size_t)bh * HD * KPAD;
  float* Ob = O + (size_t)bhl * S_LEN * HD;

  f32x4 acc_o[2][6];
  float Mst[2][4], Lst[2][4];
#pragma unroll
  for (int i = 0; i < 2; ++i) {
#pragma unroll
    for (int j = 0; j < 6; ++j) acc_o[i][j] = (f32x4){0.f, 0.f, 0.f, 0.f};
#pragma unroll
    for (int r = 0; r < 4; ++r) { Mst[i][r] = -1e30f; Lst[i][r] = 0.f; }
  }

  // prologue: QL (6 instrs/wave) + E0 of tile 0 into B0
#pragma unroll
  for (int i = 0; i < 6; ++i) {
    int rq = w * 8 + rl;
    int rg = m0 + rq; if (rg > S_LEN - 1) rg = S_LEN - 1;
    load_lds16(Qp + (size_t)rg * DMODEL + ((cs ^ (rq & 7)) * 8) + i * 64,
               QL + i * 4096 + (w * 8) * 64);
  }
  { const int l0p = 856 - m0; STAGE_E(B0, 0, l0p); }

  for (int t = 0; t < FNT; ++t) {
    const int kv0 = t * FKV;
    const int l0 = kv0 - m0 + 856;

    // ---- T phase: acc_t = Q * E^T  (cols l0..l0+255) ----
    f32x4 acc_t[2][4];
#pragma unroll
    for (int i = 0; i < 2; ++i)
#pragma unroll
      for (int j = 0; j < 4; ++j) acc_t[i][j] = (f32x4){0.f, 0.f, 0.f, 0.f};

    GSLOT_T(B0, 0, STAGE_E(B1, 1, l0), WAITVM(4));
    GSLOT_T(B1, 1, STAGE_E(B0, 2, l0), WAITVM(4));
    GSLOT_T(B0, 2, STAGE_E(B1, 3, l0), WAITVM(4));
    GSLOT_T(B1, 3, STAGE_E(B0, 4, l0), WAITVM(4));
    GSLOT_T(B0, 4, STAGE_E(B1, 5, l0), WAITVM(4));
    GSLOT_T(B1, 5, STAGE_K(B0, 0),     WAITVM(3));

    // TL write (bf16 [64][256])
#pragma unroll
    for (int i = 0; i < 2; ++i)
#pragma unroll
      for (int j = 0; j < 4; ++j)
#pragma unroll
        for (int r = 0; r < 4; ++r) {
          int row = wm * 32 + i * 16 + lq * 4 + r;
          int col = wn * 64 + j * 16 + lr;
          TLP[row * 256 + col] = f2b(acc_t[i][j][r]);
        }
    LBAR;

    // ---- S phase: acc_s = Q * K^T ----
    f32x4 acc_s[2][3];
#pragma unroll
    for (int i = 0; i < 2; ++i)
#pragma unroll
      for (int j = 0; j < 3; ++j) acc_s[i][j] = (f32x4){0.f, 0.f, 0.f, 0.f};

    GSLOT_S(B0, 0, STAGE_K(B1, 1), WAITVM(3));
    GSLOT_S(B1, 1, STAGE_K(B0, 2), WAITVM(3));
    GSLOT_S(B0, 2, STAGE_K(B1, 3), WAITVM(3));
    GSLOT_S(B1, 3, STAGE_K(B0, 4), WAITVM(3));
    GSLOT_S(B0, 4, STAGE_K(B1, 5), WAITVM(3));
    GSLOT_S(B1, 5, STAGE_V(B0, 0, 0), WAITVM(3));

    // ---- online softmax (V00 stays in flight; LDS-only barriers) ----
#pragma unroll
    for (int i = 0; i < 2; ++i)
#pragma unroll
      for (int j = 0; j < 3; ++j) {
        int jpl = wn * 48 + j * 16 + lr;
        int jp = kv0 + jpl;
#pragma unroll
        for (int r = 0; r < 4; ++r) {
          int row = wm * 32 + i * 16 + lq * 4 + r;
          float x = acc_s[i][j][r] + b2f(TLP[row * 256 + (jpl - row + 63)]);
          acc_s[i][j][r] = (jp < S_LEN) ? x : -1e30f;
        }
      }
    {
      float tm[2][4];
#pragma unroll
      for (int i = 0; i < 2; ++i)
#pragma unroll
        for (int r = 0; r < 4; ++r) {
          float v = fmaxf(fmaxf(acc_s[i][0][r], acc_s[i][1][r]), acc_s[i][2][r]);
#pragma unroll
          for (int o = 1; o < 16; o <<= 1) v = fmaxf(v, __shfl_xor(v, o));
          tm[i][r] = v;
        }
      if (lr == 0) {
#pragma unroll
        for (int i = 0; i < 2; ++i)
#pragma unroll
          for (int r = 0; r < 4; ++r)
            pmax[wn * 64 + wm * 32 + i * 16 + lq * 4 + r] = tm[i][r];
      }
    }
    LBAR;
    float fexp[2][4], ps[2][4];
#pragma unroll
    for (int i = 0; i < 2; ++i)
#pragma unroll
      for (int r = 0; r < 4; ++r) {
        int row = wm * 32 + i * 16 + lq * 4 + r;
        float M2 = fmaxf(fmaxf(pmax[row], pmax[64 + row]),
                         fmaxf(pmax[128 + row], pmax[192 + row]));
        M2 = fmaxf(M2, Mst[i][r]);
        fexp[i][r] = __expf(Mst[i][r] - M2);
        Mst[i][r] = M2;
      }
#pragma unroll
    for (int i = 0; i < 2; ++i)
#pragma unroll
      for (int r = 0; r < 4; ++r) {
        float s0 = 0.f;
#pragma unroll
        for (int j = 0; j < 3; ++j) {
          float p = __expf(acc_s[i][j][r] - Mst[i][r]);
          acc_s[i][j][r] = p;
          s0 += p;
        }
#pragma unroll
        for (int o = 1; o < 16; o <<= 1) s0 += __shfl_xor(s0, o);
        ps[i][r] = s0;
#pragma unroll
        for (int jj = 0; jj < 6; ++jj) acc_o[i][jj][r] *= fexp[i][r];
      }
    if (lr == 0) {
#pragma unroll
      for (int i = 0; i < 2; ++i)
#pragma unroll
        for (int r = 0; r < 4; ++r)
          psum[wn * 64 + wm * 32 + i * 16 + lq * 4 + r] = ps[i][r];
    }
    LBAR;
#pragma unroll
    for (int i = 0; i < 2; ++i)
#pragma unroll
      for (int r = 0; r < 4; ++r) {
        int row = wm * 32 + i * 16 + lq * 4 + r;
        float ts = psum[row] + psum[64 + row] + psum[128 + row] + psum[192 + row];
        Lst[i][r] = Lst[i][r] * fexp[i][r] + ts;
      }
    // P -> PL (bf16, swizzled A-layout; aliases TL, reads finished above)
#pragma unroll
    for (int i = 0; i < 2; ++i)
#pragma unroll
      for (int j = 0; j < 3; ++j) {
        int c192 = wn * 48 + j * 16 + lr;
        int sc = c192 >> 6, c64 = c192 & 63;
#pragma unroll
        for (int r = 0; r < 4; ++r) {
          int row = wm * 32 + i * 16 + lq * 4 + r;
          int byte = sc * 8192 + row * 128 + ((c64 * 2) ^ ((row & 7) * 16));
          *(short*)((char*)TLP + byte) = f2b(acc_s[i][j][r]);
        }
      }
    LBAR;

    // ---- PV phase: O += P * V ----
    GSLOT_PV(B0, 0, 0, STAGE_V(B1, 0, 1), WAITVM(3));
    GSLOT_PV(B1, 1, 0, STAGE_V(B0, 0, 2), WAITVM(3));
    GSLOT_PV(B0, 2, 0, STAGE_V(B1, 1, 0), WAITVM(3));
    GSLOT_PV(B1, 0, 1, STAGE_V(B0, 1, 1), WAITVM(3));
    GSLOT_PV(B0, 1, 1, STAGE_V(B1, 1, 2), WAITVM(3));
    if (t < FNT - 1) {
      GSLOT_PV(B1, 2, 1, STAGE_E(B0, 0, l0 + FKV), WAITVM(4));
    } else {
      GSLOT_PV(B1, 2, 1, NOISSUE, WAITVM(0));
    }
  }

  // ---- epilogue: O / L, store to O-scratch ----
#pragma unroll
  for (int i = 0; i < 2; ++i)
#pragma unroll
    for (int r = 0; r < 4; ++r) {
      int m = m0 + wm * 32 + i * 16 + lq * 4 + r;
      if (m < S_LEN) {
        float rs = 1.0f / Lst[i][r];
#pragma unroll
        for (int jj = 0; jj < 6; ++jj) {
          int d = (jj / 3) * 192 + wn * 48 + (jj % 3) * 16 + lr;
          Ob[(size_t)m * HD + d] = acc_o[i][jj][r] * rs;
        }
      }
    }
}

// O-scratch [16][920][384] f32 -> d_out (overwrites this half's Q/K slabs)
__global__ __launch_bounds__(256) void k_copy_o(const float* __restrict__ O,
                                                float* __restrict__ out, int b0) {
  int i = blockIdx.x * 256 + threadIdx.x;
  if (i >= 16 * S_LEN * HD / 4) return;
  const int per_bh = S_LEN * HD / 4;       // 88320
  int bhl = i / per_bh, rem = i - bhl * per_bh;
  int m = rem / (HD / 4), d4 = rem - m * (HD / 4);
  int b = b0 + (bhl >> 2), h = bhl & 3;
  float4 v = ((const float4*)O)[i];
  ((float4*)out)[((size_t)(b * S_LEN + m) * DMODEL + h * HD + d4 * 4) >> 2] = v;
}

// ---------------------------------------------------------------------------
extern "C" void kernel_launch(void* const* d_in, const int* in_sizes, int n_in,
                              void* d_out, int out_size, void* d_ws, size_t ws_size,
                              hipStream_t stream) {
  const float* hs = (const float*)d_in[0];
  const float* wq = (const float*)d_in[1];
  const float* wk = (const float*)d_in[2];
  const float* wv = (const float*)d_in[3];
  const float* de = (const float*)d_in[4];
  char* ws = (char*)d_ws;

  // layout: [Xb 22.6MB | also O-scratch][Wt 14.2MB][Eb 1.4MB][Vt 23.6MB] = 61.8MB
  short* Xb = (short*)(ws + 0);
  short* Wt = (short*)(ws + 22609920UL);
  short* Eb = (short*)(ws + 36765696UL);
  short* Vt = (short*)(ws + 36765696UL + EB_BYTES);
  float* Og = (float*)(ws + 0);          // aliases Xb (dead after qkv)
  short* out16 = (short*)d_out;

  k_cast<<<(MTOT * DMODEL / 4 + 255) / 256, 256, 0, stream>>>(hs, Xb, MTOT * DMODEL / 4);
  k_prep_ev<<<(EB_N4 + PAD_N + 255) / 256, 256, 0, stream>>>(de, Eb, Vt);
  k_transpose_w<<<dim3(48, 48, 3), dim3(32, 8, 1), 0, stream>>>(wq, wk, wv, Wt);

  k_gemm_qkv<<<dim3(232, 1, 3), 512, 0, stream>>>(Xb, Wt, out16, Vt);

  for (int hf = 0; hf < 2; ++hf) {
    k_fused<<<dim3(240), 512, 0, stream>>>(out16, Vt, Eb, Og, hf);
    k_copy_o<<<dim3(5520), 256, 0, stream>>>(Og, (float*)d_out, hf * 4);
  }
}

// Round 10
// 426.358 us; speedup vs baseline: 1.0222x; 1.0222x over previous
//
#include <hip/hip_runtime.h>

#define S_LEN 920
#define DMODEL 1536
#define NH 4
#define HD 384
#define LREL 1839
#define BATCH 8
#define MTOT (BATCH * S_LEN)   // 7360
#define KPAD 960               // padded key-dim (Vt cols)
#define NBH (BATCH * NH)       // 32

// ---- Q/K live inside d_out (shorts). Per 2-batch pair p, shorts
// [p*CHS, (p+1)*CHS) hold [Q(2p),K(2p),Q(2p+1),K(2p+1)].  The fused kernel for
// half h reads batches 4h..4h+3; its O goes to scratch; k_copy_o then writes
// d_out, overwriting exactly those batches' Q/K slabs (all reads done).
#define CHS   5652480UL        // pair stride in shorts
#define BSLAB 2826240UL        // per-batch Q+K slab in shorts
#define KOFF  1413120UL        // K offset within batch slab (shorts)

#define EB_BYTES 1412352UL
#define VT_BYTES 23592960UL

typedef __attribute__((ext_vector_type(8))) short  s16x8;
typedef __attribute__((ext_vector_type(4))) short  s16x4;
typedef __attribute__((ext_vector_type(8))) __bf16 bf16x8;
typedef __attribute__((ext_vector_type(4))) float  f32x4;

__device__ __forceinline__ short f2b(float x) {
  unsigned u = __builtin_bit_cast(unsigned, x);
  unsigned r = (u + 0x7FFFu + ((u >> 16) & 1u)) >> 16;
  return (short)r;
}
__device__ __forceinline__ float b2f(short s) {
  unsigned u = ((unsigned)(unsigned short)s) << 16;
  return __builtin_bit_cast(float, u);
}

__device__ __forceinline__ void load_lds16(const short* g, short* lds) {
  __builtin_amdgcn_global_load_lds(
      (const __attribute__((address_space(1))) void*)g,
      (__attribute__((address_space(3))) void*)lds, 16, 0, 0);
}

__device__ __forceinline__ f32x4 mfma_bf16(s16x8 a, s16x8 b, f32x4 c) {
  return __builtin_amdgcn_mfma_f32_16x16x32_bf16(
      __builtin_bit_cast(bf16x8, a), __builtin_bit_cast(bf16x8, b), c, 0, 0, 0);
}

// swizzled ds_read of one MFMA fragment (row stride 128 B, XOR 16B-slot).
__device__ __forceinline__ s16x8 frag_swz(const short* base, int row, int kk, int lq) {
  int byte = (row << 7) + (kk << 6) + (lq << 4);
  byte ^= (row & 7) << 4;
  return *(const s16x8*)((const char*)base + byte);
}

// ---------------------------------------------------------------------------
// Pipelined 256x192 GEMM core (qkv) — proven.
// ---------------------------------------------------------------------------
template <int NT>
__device__ __forceinline__ void gemm_pipe(short* smem,
    const short* __restrict__ A, int ldA, int mClamp, int m0,
    const short* __restrict__ B, int ldB, int nClamp, int n0,
    f32x4 acc[4][6]) {
  short* const A0 = smem;
  short* const B0 = smem + 16384;
  short* const A1 = smem + 28672;
  short* const B1 = smem + 45056;

  const int tid = threadIdx.x, w = tid >> 6, lane = tid & 63;
  const int lr = lane & 15, lq = lane >> 4;
  const int wr = w >> 1, wc = w & 1;

  const short* pa[4]; int la[4];
  const short* pb[3]; int lb[3];
  {
    const int rl = lane >> 3, c = lane & 7;
#pragma unroll
    for (int i = 0; i < 4; ++i) {
      int r = w * 32 + i * 8 + rl;
      int ra = m0 + r; if (ra > mClamp) ra = mClamp;
      pa[i] = A + (size_t)ra * ldA + ((c ^ (r & 7)) * 8);
      la[i] = (w * 32 + i * 8) * 64;
    }
#pragma unroll
    for (int i = 0; i < 3; ++i) {
      int r = w * 24 + i * 8 + rl;
      int rb = n0 + r; if (rb > nClamp) rb = nClamp;
      pb[i] = B + (size_t)rb * ldB + ((c ^ (r & 7)) * 8);
      lb[i] = (w * 24 + i * 8) * 64;
    }
  }

#pragma unroll
  for (int i = 0; i < 4; ++i)
#pragma unroll
    for (int j = 0; j < 6; ++j) acc[i][j] = (f32x4){0.f, 0.f, 0.f, 0.f};

#pragma unroll
  for (int i = 0; i < 4; ++i) load_lds16(pa[i], A0 + la[i]);
#pragma unroll
  for (int i = 0; i < 3; ++i) load_lds16(pb[i], B0 + lb[i]);

  for (int kt = 0; kt < NT; ++kt) {
    short* const Ab = (kt & 1) ? A1 : A0;
    short* const Bb = (kt & 1) ? B1 : B0;
    short* const An = (kt & 1) ? A0 : A1;
    short* const Bn = (kt & 1) ? B0 : B1;

    if (kt + 1 < NT) {
      const int k0 = (kt + 1) * 64;
#pragma unroll
      for (int i = 0; i < 4; ++i) load_lds16(pa[i] + k0, An + la[i]);
#pragma unroll
      for (int i = 0; i < 3; ++i) load_lds16(pb[i] + k0, Bn + lb[i]);
      asm volatile("s_waitcnt vmcnt(7)" ::: "memory");
    } else {
      asm volatile("s_waitcnt vmcnt(0)" ::: "memory");
    }
    __builtin_amdgcn_sched_barrier(0);
    __builtin_amdgcn_s_barrier();
    __builtin_amdgcn_sched_barrier(0);

    s16x8 a[4], bb[3];
#pragma unroll
    for (int f = 0; f < 4; ++f) a[f] = frag_swz(Ab, wr * 64 + f * 16 + lr, 0, lq);
#pragma unroll
    for (int f = 0; f < 3; ++f) bb[f] = frag_swz(Bb, wc * 96 + f * 16 + lr, 0, lq);
    __builtin_amdgcn_s_barrier();
    __builtin_amdgcn_s_setprio(1);
#pragma unroll
    for (int i = 0; i < 4; ++i)
#pragma unroll
      for (int j = 0; j < 3; ++j) acc[i][j] = mfma_bf16(a[i], bb[j], acc[i][j]);
    __builtin_amdgcn_s_setprio(0);
    __builtin_amdgcn_s_barrier();
#pragma unroll
    for (int f = 0; f < 3; ++f) bb[f] = frag_swz(Bb, wc * 96 + (3 + f) * 16 + lr, 0, lq);
    __builtin_amdgcn_s_barrier();
    __builtin_amdgcn_s_setprio(1);
#pragma unroll
    for (int i = 0; i < 4; ++i)
#pragma unroll
      for (int j = 0; j < 3; ++j) acc[i][3 + j] = mfma_bf16(a[i], bb[j], acc[i][3 + j]);
    __builtin_amdgcn_s_setprio(0);
    __builtin_amdgcn_s_barrier();
#pragma unroll
    for (int f = 0; f < 4; ++f) a[f] = frag_swz(Ab, wr * 64 + f * 16 + lr, 1, lq);
#pragma unroll
    for (int f = 0; f < 3; ++f) bb[f] = frag_swz(Bb, wc * 96 + f * 16 + lr, 1, lq);
    __builtin_amdgcn_s_barrier();
    __builtin_amdgcn_s_setprio(1);
#pragma unroll
    for (int i = 0; i < 4; ++i)
#pragma unroll
      for (int j = 0; j < 3; ++j) acc[i][j] = mfma_bf16(a[i], bb[j], acc[i][j]);
    __builtin_amdgcn_s_setprio(0);
    __builtin_amdgcn_s_barrier();
#pragma unroll
    for (int f = 0; f < 3; ++f) bb[f] = frag_swz(Bb, wc * 96 + (3 + f) * 16 + lr, 1, lq);
    __builtin_amdgcn_s_barrier();
    __builtin_amdgcn_s_setprio(1);
#pragma unroll
    for (int i = 0; i < 4; ++i)
#pragma unroll
      for (int j = 0; j < 3; ++j) acc[i][3 + j] = mfma_bf16(a[i], bb[j], acc[i][3 + j]);
    __builtin_amdgcn_s_setprio(0);
    __builtin_amdgcn_s_barrier();
  }
}

// ---------------------------------------------------------------------------
__global__ void k_cast(const float* __restrict__ X, short* __restrict__ O, int n4) {
  int i = blockIdx.x * blockDim.x + threadIdx.x;
  if (i >= n4) return;
  float4 v = ((const float4*)X)[i];
  s16x4 o = {f2b(v.x), f2b(v.y), f2b(v.z), f2b(v.w)};
  *(s16x4*)&O[(size_t)i * 4] = o;
}

// merged: cast distance_embedding -> Eb  AND  zero Vt pad columns (disjoint).
#define EB_N4   (LREL * HD / 4)                   // 176544
#define PAD_N   (NBH * HD * (KPAD - S_LEN))       // 491520
__global__ void k_prep_ev(const float* __restrict__ de, short* __restrict__ Eb,
                          short* __restrict__ Vt) {
  int i = blockIdx.x * blockDim.x + threadIdx.x;
  if (i < EB_N4) {
    float4 v = ((const float4*)de)[i];
    s16x4 o = {f2b(v.x), f2b(v.y), f2b(v.z), f2b(v.w)};
    *(s16x4*)&Eb[(size_t)i * 4] = o;
  } else {
    int idx = i - EB_N4;
    if (idx < PAD_N) {
      int bhd = idx / (KPAD - S_LEN);
      int s = S_LEN + idx - bhd * (KPAD - S_LEN);
      Vt[(size_t)bhd * KPAD + s] = 0;
    }
  }
}

__global__ void k_transpose_w(const float* __restrict__ W0, const float* __restrict__ W1,
                              const float* __restrict__ W2, short* __restrict__ Wt) {
  const float* W = (blockIdx.z == 0) ? W0 : ((blockIdx.z == 1) ? W1 : W2);
  short* O = Wt + (size_t)blockIdx.z * DMODEL * DMODEL;
  __shared__ float t[32][33];
  int tx = threadIdx.x, ty = threadIdx.y;
  int n0 = blockIdx.x * 32, k0 = blockIdx.y * 32;
#pragma unroll
  for (int i = 0; i < 4; ++i)
    t[ty + i * 8][tx] = W[(size_t)(k0 + ty + i * 8) * DMODEL + n0 + tx];
  __syncthreads();
#pragma unroll
  for (int i = 0; i < 4; ++i)
    O[(size_t)(n0 + ty + i * 8) * DMODEL + k0 + tx] = f2b(t[tx][ty + i * 8]);
}

// ---------------------------------------------------------------------------
// QKV: 256x192 tile pipeline.  Grid (232,1,3), 1 block/CU.  Chunked XCD
// swizzle (round-8 configuration of the 420.6-us best; the linear n=t&7
// variant measured FETCH 258 MB vs 115 MB here — XCD-panel theory refuted).
// ---------------------------------------------------------------------------
#define QKV_NT (DMODEL / 64)   // 24 K-tiles

__global__ __launch_bounds__(512, 2) void k_gemm_qkv(const short* __restrict__ Xb,
                                                     const short* __restrict__ Wt,
                                                     short* __restrict__ out16,
                                                     short* __restrict__ Vt) {
  __shared__ short smem[57344];
  const int z = blockIdx.z;
  const int t = blockIdx.x;
  const int t2 = (t & 7) * 29 + (t >> 3);
  const int m0 = (t2 >> 3) * 256;
  const int n0 = (t2 & 7) * 192;

  const int tid = threadIdx.x, w = tid >> 6, lane = tid & 63;
  const int lr = lane & 15, lq = lane >> 4;
  const int wr = w >> 1, wc = w & 1;

  f32x4 acc[4][6];
  gemm_pipe<QKV_NT>(smem, Xb, DMODEL, MTOT - 1, m0,
                    Wt + (size_t)z * DMODEL * DMODEL, DMODEL, DMODEL - 1, n0, acc);

  __syncthreads();
  const float inv = 0.05103103630798287f;       // 1/sqrt(384)
  if (z != 2) {
    short* T = smem;                            // [256][200]
#pragma unroll
    for (int i = 0; i < 4; ++i)
#pragma unroll
      for (int j = 0; j < 6; ++j) {
        int ml = wr * 64 + i * 16 + lq * 4;
        int nl = wc * 96 + j * 16 + lr;
#pragma unroll
        for (int r = 0; r < 4; ++r) {
          float v = acc[i][j][r];
          T[(ml + r) * 200 + nl] = f2b(z == 0 ? v * inv : v);
        }
      }
    __syncthreads();
    for (int u = 0; u < 12; ++u) {
      int unit = u * 512 + tid;
      int ml = unit / 24, c = unit - ml * 24;
      int m = m0 + ml;
      if (m < MTOT) {
        int b = m / S_LEN, s = m - b * S_LEN;
        short* dst = out16 + (size_t)(b >> 1) * CHS + (size_t)(b & 1) * BSLAB +
                     (z == 1 ? KOFF : 0UL) + (size_t)s * DMODEL + n0 + c * 8;
        *(s16x8*)dst = *(const s16x8*)&T[ml * 200 + c * 8];
      }
    }
  } else {
    short* T = smem;                            // [192][264] transposed
#pragma unroll
    for (int i = 0; i < 4; ++i)
#pragma unroll
      for (int j = 0; j < 6; ++j) {
        int ml = wr * 64 + i * 16 + lq * 4;
        int nl = wc * 96 + j * 16 + lr;
#pragma unroll
        for (int r = 0; r < 4; ++r)
          T[nl * 264 + ml + r] = f2b(acc[i][j][r]);
      }
    __syncthreads();
    const int h = n0 / HD;
    const int d0 = n0 - h * HD;
    for (int u = 0; u < 12; ++u) {
      int unit = u * 512 + tid;
      int nl = unit >> 5, c = unit & 31;
      int m = m0 + c * 8;
      if (m < MTOT) {
        int b = m / S_LEN, s = m - b * S_LEN;
        size_t row = (size_t)(b * NH + h) * HD + d0 + nl;
        *(s16x8*)&Vt[row * KPAD + s] = *(const s16x8*)&T[nl * 264 + c * 8];
      }
    }
  }
}

// ---------------------------------------------------------------------------
// FUSED attention v1 (best measured): per block one bh x 64 q-rows.
// 5 KV-tiles of 192 keys.  Per tile: 6 E-slots (T=Q*E^T -> TL bf16), 6 K-slots
// (S=Q*K^T), online softmax (P -> PL aliasing TL), 6 V-slots (O += P*V).
// Counted-vmcnt ring, swizzled LDS, setprio MFMA clusters.
// ---------------------------------------------------------------------------
#define FKV 192
#define FNT 5

#define WAITVM(N) { asm volatile("s_waitcnt vmcnt(" #N ")" ::: "memory"); \
  __builtin_amdgcn_sched_barrier(0); __builtin_amdgcn_s_barrier(); \
  __builtin_amdgcn_sched_barrier(0); }

#define LBAR { asm volatile("s_waitcnt lgkmcnt(0)" ::: "memory"); \
  __builtin_amdgcn_sched_barrier(0); __builtin_amdgcn_s_barrier(); \
  __builtin_amdgcn_sched_barrier(0); }

#define NOISSUE { }

#define STAGE_E(BUF, C, L0) { \
  _Pragma("unroll") for (int i_ = 0; i_ < 4; ++i_) { \
    int r_ = w * 32 + i_ * 8 + rl; \
    int rg_ = (L0) + r_; rg_ = rg_ < 0 ? 0 : (rg_ > LREL - 1 ? LREL - 1 : rg_); \
    load_lds16(Eb + (size_t)rg_ * HD + ((cs ^ (r_ & 7)) * 8) + (C) * 64, \
               (BUF) + (w * 32 + i_ * 8) * 64); } }

#define STAGE_K(BUF, C) { \
  _Pragma("unroll") for (int i_ = 0; i_ < 3; ++i_) { \
    int r_ = w * 24 + i_ * 8 + rl; \
    int rg_ = kv0 + r_; if (rg_ > S_LEN - 1) rg_ = S_LEN - 1; \
    load_lds16(Kp + (size_t)rg_ * DMODEL + ((cs ^ (r_ & 7)) * 8) + (C) * 64, \
               (BUF) + (w * 24 + i_ * 8) * 64); } }

#define STAGE_V(BUF, HF, SC) { \
  _Pragma("unroll") for (int i_ = 0; i_ < 3; ++i_) { \
    int r_ = w * 24 + i_ * 8 + rl; \
    load_lds16(Vb + (size_t)((HF) * 192 + r_) * KPAD + kv0 + (SC) * 64 + ((cs ^ (r_ & 7)) * 8), \
               (BUF) + (w * 24 + i_ * 8) * 64); } }

#define GSLOT_T(CUR, C, ISSUE, WVM) { ISSUE; WVM; \
  s16x8 a_[2][2], b_[2][4]; \
  _Pragma("unroll") for (int k_ = 0; k_ < 2; ++k_) { \
    _Pragma("unroll") for (int i_ = 0; i_ < 2; ++i_) \
      a_[i_][k_] = frag_swz(QL + (C) * 4096, wm * 32 + i_ * 16 + lr, k_, lq); \
    _Pragma("unroll") for (int j_ = 0; j_ < 4; ++j_) \
      b_[k_][j_] = frag_swz((CUR), wn * 64 + j_ * 16 + lr, k_, lq); } \
  __builtin_amdgcn_s_setprio(1); \
  _Pragma("unroll") for (int k_ = 0; k_ < 2; ++k_) \
    _Pragma("unroll") for (int i_ = 0; i_ < 2; ++i_) \
      _Pragma("unroll") for (int j_ = 0; j_ < 4; ++j_) \
        acc_t[i_][j_] = mfma_bf16(a_[i_][k_], b_[k_][j_], acc_t[i_][j_]); \
  __builtin_amdgcn_s_setprio(0); __builtin_amdgcn_s_barrier(); }

#define GSLOT_S(CUR, C, ISSUE, WVM) { ISSUE; WVM; \
  s16x8 a_[2][2], b_[2][3]; \
  _Pragma("unroll") for (int k_ = 0; k_ < 2; ++k_) { \
    _Pragma("unroll") for (int i_ = 0; i_ < 2; ++i_) \
      a_[i_][k_] = frag_swz(QL + (C) * 4096, wm * 32 + i_ * 16 + lr, k_, lq); \
    _Pragma("unroll") for (int j_ = 0; j_ < 3; ++j_) \
      b_[k_][j_] = frag_swz((CUR), wn * 48 + j_ * 16 + lr, k_, lq); } \
  __builtin_amdgcn_s_setprio(1); \
  _Pragma("unroll") for (int k_ = 0; k_ < 2; ++k_) \
    _Pragma("unroll") for (int i_ = 0; i_ < 2; ++i_) \
      _Pragma("unroll") for (int j_ = 0; j_ < 3; ++j_) \
        acc_s[i_][j_] = mfma_bf16(a_[i_][k_], b_[k_][j_], acc_s[i_][j_]); \
  __builtin_amdgcn_s_setprio(0); __builtin_amdgcn_s_barrier(); }

#define GSLOT_PV(CUR, SC, HF, ISSUE, WVM) { ISSUE; WVM; \
  s16x8 a_[2][2], b_[2][3]; \
  _Pragma("unroll") for (int k_ = 0; k_ < 2; ++k_) { \
    _Pragma("unroll") for (int i_ = 0; i_ < 2; ++i_) \
      a_[i_][k_] = frag_swz(TLP + (SC) * 4096, wm * 32 + i_ * 16 + lr, k_, lq); \
    _Pragma("unroll") for (int j_ = 0; j_ < 3; ++j_) \
      b_[k_][j_] = frag_swz((CUR), wn * 48 + j_ * 16 + lr, k_, lq); } \
  __builtin_amdgcn_s_setprio(1); \
  _Pragma("unroll") for (int k_ = 0; k_ < 2; ++k_) \
    _Pragma("unroll") for (int i_ = 0; i_ < 2; ++i_) \
      _Pragma("unroll") for (int j_ = 0; j_ < 3; ++j_) \
        acc_o[i_][(HF) * 3 + j_] = mfma_bf16(a_[i_][k_], b_[k_][j_], acc_o[i_][(HF) * 3 + j_]); \
  __builtin_amdgcn_s_setprio(0); __builtin_amdgcn_s_barrier(); }

__global__ __launch_bounds__(512, 1) void k_fused(const short* __restrict__ out16,
                                                  const short* __restrict__ Vt,
                                                  const short* __restrict__ Eb,
                                                  float* __restrict__ O, int half) {
  __shared__ short smem[74752];          // 149.5 KB
  short* const QL  = smem;               // 6 chunks [64][64]   (24576)
  short* const B0  = smem + 24576;       // [256][64]           (16384)
  short* const B1  = smem + 40960;       // [256][64]           (16384)
  short* const TLP = smem + 57344;       // TL [64][256] / PL 3x[64][64] (16384)
  float* const pmax = (float*)(smem + 73728);   // [4][64]
  float* const psum = pmax + 256;               // [4][64]

  const int f  = blockIdx.x;             // [0,240)
  const int f2 = (f & 7) * 30 + (f >> 3);
  const int mt = f2 % 15, bhl = f2 / 15;
  const int bh = half * 16 + bhl, b = bh >> 2, h = bh & 3;
  const int m0 = mt * 64;

  const int tid = threadIdx.x, w = tid >> 6, lane = tid & 63;
  const int lr = lane & 15, lq = lane >> 4;
  const int wm = w >> 2, wn = w & 3;     // 2m x 4n waves; wave = 32 rows x 48 cols
  const int rl = lane >> 3, cs = lane & 7;

  const short* Qp = out16 + (size_t)(b >> 1) * CHS + (size_t)(b & 1) * BSLAB + h * HD;
  const short* Kp = Qp + KOFF;
  const short* Vb = Vt + (size_t)bh * HD * KPAD;
  float* Ob = O + (size_t)bhl * S_LEN * HD;

  f32x4 acc_o[2][6];
  float Mst[2][4], Lst[2][4];
#pragma unroll
  for (int i = 0; i < 2; ++i) {
#pragma unroll
    for (int j = 0; j < 6; ++j) acc_o[i][j] = (f32x4){0.f, 0.f, 0.f, 0.f};
#pragma unroll
    for (int r = 0; r < 4; ++r) { Mst[i][r] = -1e30f; Lst[i][r] = 0.f; }
  }

  // prologue: QL (6 instrs/wave) + E0 of tile 0 into B0
#pragma unroll
  for (int i = 0; i < 6; ++i) {
    int rq = w * 8 + rl;
    int rg = m0 + rq; if (rg > S_LEN - 1) rg = S_LEN - 1;
    load_lds16(Qp + (size_t)rg * DMODEL + ((cs ^ (rq & 7)) * 8) + i * 64,
               QL + i * 4096 + (w * 8) * 64);
  }
  { const int l0p = 856 - m0; STAGE_E(B0, 0, l0p); }

  for (int t = 0; t < FNT; ++t) {
    const int kv0 = t * FKV;
    const int l0 = kv0 - m0 + 856;

    // ---- T phase: acc_t = Q * E^T  (cols l0..l0+255) ----
    f32x4 acc_t[2][4];
#pragma unroll
    for (int i = 0; i < 2; ++i)
#pragma unroll
      for (int j = 0; j < 4; ++j) acc_t[i][j] = (f32x4){0.f, 0.f, 0.f, 0.f};

    GSLOT_T(B0, 0, STAGE_E(B1, 1, l0), WAITVM(4));
    GSLOT_T(B1, 1, STAGE_E(B0, 2, l0), WAITVM(4));
    GSLOT_T(B0, 2, STAGE_E(B1, 3, l0), WAITVM(4));
    GSLOT_T(B1, 3, STAGE_E(B0, 4, l0), WAITVM(4));
    GSLOT_T(B0, 4, STAGE_E(B1, 5, l0), WAITVM(4));
    GSLOT_T(B1, 5, STAGE_K(B0, 0),     WAITVM(3));

    // TL write (bf16 [64][256])
#pragma unroll
    for (int i = 0; i < 2; ++i)
#pragma unroll
      for (int j = 0; j < 4; ++j)
#pragma unroll
        for (int r = 0; r < 4; ++r) {
          int row = wm * 32 + i * 16 + lq * 4 + r;
          int col = wn * 64 + j * 16 + lr;
          TLP[row * 256 + col] = f2b(acc_t[i][j][r]);
        }
    LBAR;

    // ---- S phase: acc_s = Q * K^T ----
    f32x4 acc_s[2][3];
#pragma unroll
    for (int i = 0; i < 2; ++i)
#pragma unroll
      for (int j = 0; j < 3; ++j) acc_s[i][j] = (f32x4){0.f, 0.f, 0.f, 0.f};

    GSLOT_S(B0, 0, STAGE_K(B1, 1), WAITVM(3));
    GSLOT_S(B1, 1, STAGE_K(B0, 2), WAITVM(3));
    GSLOT_S(B0, 2, STAGE_K(B1, 3), WAITVM(3));
    GSLOT_S(B1, 3, STAGE_K(B0, 4), WAITVM(3));
    GSLOT_S(B0, 4, STAGE_K(B1, 5), WAITVM(3));
    GSLOT_S(B1, 5, STAGE_V(B0, 0, 0), WAITVM(3));

    // ---- online softmax (V00 stays in flight; LDS-only barriers) ----
#pragma unroll
    for (int i = 0; i < 2; ++i)
#pragma unroll
      for (int j = 0; j < 3; ++j) {
        int jpl = wn * 48 + j * 16 + lr;
        int jp = kv0 + jpl;
#pragma unroll
        for (int r = 0; r < 4; ++r) {
          int row = wm * 32 + i * 16 + lq * 4 + r;
          float x = acc_s[i][j][r] + b2f(TLP[row * 256 + (jpl - row + 63)]);
          acc_s[i][j][r] = (jp < S_LEN) ? x : -1e30f;
        }
      }
    {
      float tm[2][4];
#pragma unroll
      for (int i = 0; i < 2; ++i)
#pragma unroll
        for (int r = 0; r < 4; ++r) {
          float v = fmaxf(fmaxf(acc_s[i][0][r], acc_s[i][1][r]), acc_s[i][2][r]);
#pragma unroll
          for (int o = 1; o < 16; o <<= 1) v = fmaxf(v, __shfl_xor(v, o));
          tm[i][r] = v;
        }
      if (lr == 0) {
#pragma unroll
        for (int i = 0; i < 2; ++i)
#pragma unroll
          for (int r = 0; r < 4; ++r)
            pmax[wn * 64 + wm * 32 + i * 16 + lq * 4 + r] = tm[i][r];
      }
    }
    LBAR;
    float fexp[2][4], ps[2][4];
#pragma unroll
    for (int i = 0; i < 2; ++i)
#pragma unroll
      for (int r = 0; r < 4; ++r) {
        int row = wm * 32 + i * 16 + lq * 4 + r;
        float M2 = fmaxf(fmaxf(pmax[row], pmax[64 + row]),
                         fmaxf(pmax[128 + row], pmax[192 + row]));
        M2 = fmaxf(M2, Mst[i][r]);
        fexp[i][r] = __expf(Mst[i][r] - M2);
        Mst[i][r] = M2;
      }
#pragma unroll
    for (int i = 0; i < 2; ++i)
#pragma unroll
      for (int r = 0; r < 4; ++r) {
        float s0 = 0.f;
#pragma unroll
        for (int j = 0; j < 3; ++j) {
          float p = __expf(acc_s[i][j][r] - Mst[i][r]);
          acc_s[i][j][r] = p;
          s0 += p;
        }
#pragma unroll
        for (int o = 1; o < 16; o <<= 1) s0 += __shfl_xor(s0, o);
        ps[i][r] = s0;
#pragma unroll
        for (int jj = 0; jj < 6; ++jj) acc_o[i][jj][r] *= fexp[i][r];
      }
    if (lr == 0) {
#pragma unroll
      for (int i = 0; i < 2; ++i)
#pragma unroll
        for (int r = 0; r < 4; ++r)
          psum[wn * 64 + wm * 32 + i * 16 + lq * 4 + r] = ps[i][r];
    }
    LBAR;
#pragma unroll
    for (int i = 0; i < 2; ++i)
#pragma unroll
      for (int r = 0; r < 4; ++r) {
        int row = wm * 32 + i * 16 + lq * 4 + r;
        float ts = psum[row] + psum[64 + row] + psum[128 + row] + psum[192 + row];
        Lst[i][r] = Lst[i][r] * fexp[i][r] + ts;
      }
    // P -> PL (bf16, swizzled A-layout; aliases TL, reads finished above)
#pragma unroll
    for (int i = 0; i < 2; ++i)
#pragma unroll
      for (int j = 0; j < 3; ++j) {
        int c192 = wn * 48 + j * 16 + lr;
        int sc = c192 >> 6, c64 = c192 & 63;
#pragma unroll
        for (int r = 0; r < 4; ++r) {
          int row = wm * 32 + i * 16 + lq * 4 + r;
          int byte = sc * 8192 + row * 128 + ((c64 * 2) ^ ((row & 7) * 16));
          *(short*)((char*)TLP + byte) = f2b(acc_s[i][j][r]);
        }
      }
    LBAR;

    // ---- PV phase: O += P * V ----
    GSLOT_PV(B0, 0, 0, STAGE_V(B1, 0, 1), WAITVM(3));
    GSLOT_PV(B1, 1, 0, STAGE_V(B0, 0, 2), WAITVM(3));
    GSLOT_PV(B0, 2, 0, STAGE_V(B1, 1, 0), WAITVM(3));
    GSLOT_PV(B1, 0, 1, STAGE_V(B0, 1, 1), WAITVM(3));
    GSLOT_PV(B0, 1, 1, STAGE_V(B1, 1, 2), WAITVM(3));
    if (t < FNT - 1) {
      GSLOT_PV(B1, 2, 1, STAGE_E(B0, 0, l0 + FKV), WAITVM(4));
    } else {
      GSLOT_PV(B1, 2, 1, NOISSUE, WAITVM(0));
    }
  }

  // ---- epilogue: O / L, store to O-scratch ----
#pragma unroll
  for (int i = 0; i < 2; ++i)
#pragma unroll
    for (int r = 0; r < 4; ++r) {
      int m = m0 + wm * 32 + i * 16 + lq * 4 + r;
      if (m < S_LEN) {
        float rs = 1.0f / Lst[i][r];
#pragma unroll
        for (int jj = 0; jj < 6; ++jj) {
          int d = (jj / 3) * 192 + wn * 48 + (jj % 3) * 16 + lr;
          Ob[(size_t)m * HD + d] = acc_o[i][jj][r] * rs;
        }
      }
    }
}

// O-scratch [16][920][384] f32 -> d_out (overwrites this half's Q/K slabs)
__global__ __launch_bounds__(256) void k_copy_o(const float* __restrict__ O,
                                                float* __restrict__ out, int b0) {
  int i = blockIdx.x * 256 + threadIdx.x;
  if (i >= 16 * S_LEN * HD / 4) return;
  const int per_bh = S_LEN * HD / 4;       // 88320
  int bhl = i / per_bh, rem = i - bhl * per_bh;
  int m = rem / (HD / 4), d4 = rem - m * (HD / 4);
  int b = b0 + (bhl >> 2), h = bhl & 3;
  float4 v = ((const float4*)O)[i];
  ((float4*)out)[((size_t)(b * S_LEN + m) * DMODEL + h * HD + d4 * 4) >> 2] = v;
}

// ---------------------------------------------------------------------------
extern "C" void kernel_launch(void* const* d_in, const int* in_sizes, int n_in,
                              void* d_out, int out_size, void* d_ws, size_t ws_size,
                              hipStream_t stream) {
  const float* hs = (const float*)d_in[0];
  const float* wq = (const float*)d_in[1];
  const float* wk = (const float*)d_in[2];
  const float* wv = (const float*)d_in[3];
  const float* de = (const float*)d_in[4];
  char* ws = (char*)d_ws;

  // layout: [Xb 22.6MB | also O-scratch][Wt 14.2MB][Eb 1.4MB][Vt 23.6MB] = 61.8MB
  short* Xb = (short*)(ws + 0);
  short* Wt = (short*)(ws + 22609920UL);
  short* Eb = (short*)(ws + 36765696UL);
  short* Vt = (short*)(ws + 36765696UL + EB_BYTES);
  float* Og = (float*)(ws + 0);          // aliases Xb (dead after qkv)
  short* out16 = (short*)d_out;

  k_cast<<<(MTOT * DMODEL / 4 + 255) / 256, 256, 0, stream>>>(hs, Xb, MTOT * DMODEL / 4);
  k_prep_ev<<<(EB_N4 + PAD_N + 255) / 256, 256, 0, stream>>>(de, Eb, Vt);
  k_transpose_w<<<dim3(48, 48, 3), dim3(32, 8, 1), 0, stream>>>(wq, wk, wv, Wt);

  k_gemm_qkv<<<dim3(232, 1, 3), 512, 0, stream>>>(Xb, Wt, out16, Vt);

  for (int hf = 0; hf < 2; ++hf) {
    k_fused<<<dim3(240), 512, 0, stream>>>(out16, Vt, Eb, Og, hf);
    k_copy_o<<<dim3(5520), 256, 0, stream>>>(Og, (float*)d_out, hf * 4);
  }
}

// Round 11
// 416.073 us; speedup vs baseline: 1.0475x; 1.0247x over previous
//
#include <hip/hip_runtime.h>

#define S_LEN 920
#define DMODEL 1536
#define NH 4
#define HD 384
#define LREL 1839
#define BATCH 8
#define MTOT (BATCH * S_LEN)   // 7360
#define KPAD 960               // padded key-dim (Vt cols)
#define NBH (BATCH * NH)       // 32

// ---- Fallback layout: Q/K live inside d_out (shorts). Per 2-batch pair p,
// shorts [p*CHS,(p+1)*CHS) hold [Q(2p),K(2p),Q(2p+1),K(2p+1)]; fused half h
// reads batches 4h..4h+3, O goes to scratch, k_copy_o overwrites the slabs.
// ---- Direct mode (ws_size >= 107 MB): Q/K live in workspace, one fused
// launch writes d_out directly, no copies, no aliasing discipline.
#define CHS   5652480UL        // pair stride in shorts
#define BSLAB 2826240UL        // per-batch Q+K slab in shorts
#define KOFF  1413120UL        // K offset within batch slab (shorts)

#define EB_BYTES 1412352UL
#define VT_BYTES 23592960UL
#define QW_OFF   61771008UL    // byte offset of Q in ws (direct mode)
#define KW_OFF   84380928UL    // byte offset of K in ws (direct mode)
#define WS_DIRECT 106990848UL  // required ws_size for direct mode

typedef __attribute__((ext_vector_type(8))) short  s16x8;
typedef __attribute__((ext_vector_type(4))) short  s16x4;
typedef __attribute__((ext_vector_type(8))) __bf16 bf16x8;
typedef __attribute__((ext_vector_type(4))) float  f32x4;

__device__ __forceinline__ short f2b(float x) {
  unsigned u = __builtin_bit_cast(unsigned, x);
  unsigned r = (u + 0x7FFFu + ((u >> 16) & 1u)) >> 16;
  return (short)r;
}
__device__ __forceinline__ float b2f(short s) {
  unsigned u = ((unsigned)(unsigned short)s) << 16;
  return __builtin_bit_cast(float, u);
}

__device__ __forceinline__ void load_lds16(const short* g, short* lds) {
  __builtin_amdgcn_global_load_lds(
      (const __attribute__((address_space(1))) void*)g,
      (__attribute__((address_space(3))) void*)lds, 16, 0, 0);
}

__device__ __forceinline__ f32x4 mfma_bf16(s16x8 a, s16x8 b, f32x4 c) {
  return __builtin_amdgcn_mfma_f32_16x16x32_bf16(
      __builtin_bit_cast(bf16x8, a), __builtin_bit_cast(bf16x8, b), c, 0, 0, 0);
}

// swizzled ds_read of one MFMA fragment (row stride 128 B, XOR 16B-slot).
__device__ __forceinline__ s16x8 frag_swz(const short* base, int row, int kk, int lq) {
  int byte = (row << 7) + (kk << 6) + (lq << 4);
  byte ^= (row & 7) << 4;
  return *(const s16x8*)((const char*)base + byte);
}

// ---------------------------------------------------------------------------
// Pipelined 256x192 GEMM core (qkv) — proven.
// ---------------------------------------------------------------------------
template <int NT>
__device__ __forceinline__ void gemm_pipe(short* smem,
    const short* __restrict__ A, int ldA, int mClamp, int m0,
    const short* __restrict__ B, int ldB, int nClamp, int n0,
    f32x4 acc[4][6]) {
  short* const A0 = smem;
  short* const B0 = smem + 16384;
  short* const A1 = smem + 28672;
  short* const B1 = smem + 45056;

  const int tid = threadIdx.x, w = tid >> 6, lane = tid & 63;
  const int lr = lane & 15, lq = lane >> 4;
  const int wr = w >> 1, wc = w & 1;

  const short* pa[4]; int la[4];
  const short* pb[3]; int lb[3];
  {
    const int rl = lane >> 3, c = lane & 7;
#pragma unroll
    for (int i = 0; i < 4; ++i) {
      int r = w * 32 + i * 8 + rl;
      int ra = m0 + r; if (ra > mClamp) ra = mClamp;
      pa[i] = A + (size_t)ra * ldA + ((c ^ (r & 7)) * 8);
      la[i] = (w * 32 + i * 8) * 64;
    }
#pragma unroll
    for (int i = 0; i < 3; ++i) {
      int r = w * 24 + i * 8 + rl;
      int rb = n0 + r; if (rb > nClamp) rb = nClamp;
      pb[i] = B + (size_t)rb * ldB + ((c ^ (r & 7)) * 8);
      lb[i] = (w * 24 + i * 8) * 64;
    }
  }

#pragma unroll
  for (int i = 0; i < 4; ++i)
#pragma unroll
    for (int j = 0; j < 6; ++j) acc[i][j] = (f32x4){0.f, 0.f, 0.f, 0.f};

#pragma unroll
  for (int i = 0; i < 4; ++i) load_lds16(pa[i], A0 + la[i]);
#pragma unroll
  for (int i = 0; i < 3; ++i) load_lds16(pb[i], B0 + lb[i]);

  for (int kt = 0; kt < NT; ++kt) {
    short* const Ab = (kt & 1) ? A1 : A0;
    short* const Bb = (kt & 1) ? B1 : B0;
    short* const An = (kt & 1) ? A0 : A1;
    short* const Bn = (kt & 1) ? B0 : B1;

    if (kt + 1 < NT) {
      const int k0 = (kt + 1) * 64;
#pragma unroll
      for (int i = 0; i < 4; ++i) load_lds16(pa[i] + k0, An + la[i]);
#pragma unroll
      for (int i = 0; i < 3; ++i) load_lds16(pb[i] + k0, Bn + lb[i]);
      asm volatile("s_waitcnt vmcnt(7)" ::: "memory");
    } else {
      asm volatile("s_waitcnt vmcnt(0)" ::: "memory");
    }
    __builtin_amdgcn_sched_barrier(0);
    __builtin_amdgcn_s_barrier();
    __builtin_amdgcn_sched_barrier(0);

    s16x8 a[4], bb[3];
#pragma unroll
    for (int f = 0; f < 4; ++f) a[f] = frag_swz(Ab, wr * 64 + f * 16 + lr, 0, lq);
#pragma unroll
    for (int f = 0; f < 3; ++f) bb[f] = frag_swz(Bb, wc * 96 + f * 16 + lr, 0, lq);
    __builtin_amdgcn_s_barrier();
    __builtin_amdgcn_s_setprio(1);
#pragma unroll
    for (int i = 0; i < 4; ++i)
#pragma unroll
      for (int j = 0; j < 3; ++j) acc[i][j] = mfma_bf16(a[i], bb[j], acc[i][j]);
    __builtin_amdgcn_s_setprio(0);
    __builtin_amdgcn_s_barrier();
#pragma unroll
    for (int f = 0; f < 3; ++f) bb[f] = frag_swz(Bb, wc * 96 + (3 + f) * 16 + lr, 0, lq);
    __builtin_amdgcn_s_barrier();
    __builtin_amdgcn_s_setprio(1);
#pragma unroll
    for (int i = 0; i < 4; ++i)
#pragma unroll
      for (int j = 0; j < 3; ++j) acc[i][3 + j] = mfma_bf16(a[i], bb[j], acc[i][3 + j]);
    __builtin_amdgcn_s_setprio(0);
    __builtin_amdgcn_s_barrier();
#pragma unroll
    for (int f = 0; f < 4; ++f) a[f] = frag_swz(Ab, wr * 64 + f * 16 + lr, 1, lq);
#pragma unroll
    for (int f = 0; f < 3; ++f) bb[f] = frag_swz(Bb, wc * 96 + f * 16 + lr, 1, lq);
    __builtin_amdgcn_s_barrier();
    __builtin_amdgcn_s_setprio(1);
#pragma unroll
    for (int i = 0; i < 4; ++i)
#pragma unroll
      for (int j = 0; j < 3; ++j) acc[i][j] = mfma_bf16(a[i], bb[j], acc[i][j]);
    __builtin_amdgcn_s_setprio(0);
    __builtin_amdgcn_s_barrier();
#pragma unroll
    for (int f = 0; f < 3; ++f) bb[f] = frag_swz(Bb, wc * 96 + (3 + f) * 16 + lr, 1, lq);
    __builtin_amdgcn_s_barrier();
    __builtin_amdgcn_s_setprio(1);
#pragma unroll
    for (int i = 0; i < 4; ++i)
#pragma unroll
      for (int j = 0; j < 3; ++j) acc[i][3 + j] = mfma_bf16(a[i], bb[j], acc[i][3 + j]);
    __builtin_amdgcn_s_setprio(0);
    __builtin_amdgcn_s_barrier();
  }
}

// ---------------------------------------------------------------------------
__global__ void k_cast(const float* __restrict__ X, short* __restrict__ O, int n4) {
  int i = blockIdx.x * blockDim.x + threadIdx.x;
  if (i >= n4) return;
  float4 v = ((const float4*)X)[i];
  s16x4 o = {f2b(v.x), f2b(v.y), f2b(v.z), f2b(v.w)};
  *(s16x4*)&O[(size_t)i * 4] = o;
}

// merged: cast distance_embedding -> Eb  AND  zero Vt pad columns (disjoint).
#define EB_N4   (LREL * HD / 4)                   // 176544
#define PAD_N   (NBH * HD * (KPAD - S_LEN))       // 491520
__global__ void k_prep_ev(const float* __restrict__ de, short* __restrict__ Eb,
                          short* __restrict__ Vt) {
  int i = blockIdx.x * blockDim.x + threadIdx.x;
  if (i < EB_N4) {
    float4 v = ((const float4*)de)[i];
    s16x4 o = {f2b(v.x), f2b(v.y), f2b(v.z), f2b(v.w)};
    *(s16x4*)&Eb[(size_t)i * 4] = o;
  } else {
    int idx = i - EB_N4;
    if (idx < PAD_N) {
      int bhd = idx / (KPAD - S_LEN);
      int s = S_LEN + idx - bhd * (KPAD - S_LEN);
      Vt[(size_t)bhd * KPAD + s] = 0;
    }
  }
}

__global__ void k_transpose_w(const float* __restrict__ W0, const float* __restrict__ W1,
                              const float* __restrict__ W2, short* __restrict__ Wt) {
  const float* W = (blockIdx.z == 0) ? W0 : ((blockIdx.z == 1) ? W1 : W2);
  short* O = Wt + (size_t)blockIdx.z * DMODEL * DMODEL;
  __shared__ float t[32][33];
  int tx = threadIdx.x, ty = threadIdx.y;
  int n0 = blockIdx.x * 32, k0 = blockIdx.y * 32;
#pragma unroll
  for (int i = 0; i < 4; ++i)
    t[ty + i * 8][tx] = W[(size_t)(k0 + ty + i * 8) * DMODEL + n0 + tx];
  __syncthreads();
#pragma unroll
  for (int i = 0; i < 4; ++i)
    O[(size_t)(n0 + ty + i * 8) * DMODEL + k0 + tx] = f2b(t[tx][ty + i * 8]);
}

// ---------------------------------------------------------------------------
// QKV: 256x192 tile pipeline.  Grid (232,1,3), 1 block/CU.  Chunked XCD
// swizzle (FETCH 115 MB; linear n=t&7 variant measured 258 MB — refuted).
// mode=1: Q/K go to workspace (plain [m][1536] layout); mode=0: d_out slabs.
// ---------------------------------------------------------------------------
#define QKV_NT (DMODEL / 64)   // 24 K-tiles

__global__ __launch_bounds__(512, 2) void k_gemm_qkv(const short* __restrict__ Xb,
                                                     const short* __restrict__ Wt,
                                                     short* __restrict__ out16,
                                                     short* __restrict__ Vt,
                                                     short* __restrict__ Qw,
                                                     short* __restrict__ Kw,
                                                     int mode) {
  __shared__ short smem[57344];
  const int z = blockIdx.z;
  const int t = blockIdx.x;
  const int t2 = (t & 7) * 29 + (t >> 3);
  const int m0 = (t2 >> 3) * 256;
  const int n0 = (t2 & 7) * 192;

  const int tid = threadIdx.x, w = tid >> 6, lane = tid & 63;
  const int lr = lane & 15, lq = lane >> 4;
  const int wr = w >> 1, wc = w & 1;

  f32x4 acc[4][6];
  gemm_pipe<QKV_NT>(smem, Xb, DMODEL, MTOT - 1, m0,
                    Wt + (size_t)z * DMODEL * DMODEL, DMODEL, DMODEL - 1, n0, acc);

  __syncthreads();
  const float inv = 0.05103103630798287f;       // 1/sqrt(384)
  if (z != 2) {
    short* T = smem;                            // [256][200]
#pragma unroll
    for (int i = 0; i < 4; ++i)
#pragma unroll
      for (int j = 0; j < 6; ++j) {
        int ml = wr * 64 + i * 16 + lq * 4;
        int nl = wc * 96 + j * 16 + lr;
#pragma unroll
        for (int r = 0; r < 4; ++r) {
          float v = acc[i][j][r];
          T[(ml + r) * 200 + nl] = f2b(z == 0 ? v * inv : v);
        }
      }
    __syncthreads();
    for (int u = 0; u < 12; ++u) {
      int unit = u * 512 + tid;
      int ml = unit / 24, c = unit - ml * 24;
      int m = m0 + ml;
      if (m < MTOT) {
        short* dst;
        if (mode) {
          dst = (z == 0 ? Qw : Kw) + (size_t)m * DMODEL + n0 + c * 8;
        } else {
          int b = m / S_LEN, s = m - b * S_LEN;
          dst = out16 + (size_t)(b >> 1) * CHS + (size_t)(b & 1) * BSLAB +
                (z == 1 ? KOFF : 0UL) + (size_t)s * DMODEL + n0 + c * 8;
        }
        *(s16x8*)dst = *(const s16x8*)&T[ml * 200 + c * 8];
      }
    }
  } else {
    short* T = smem;                            // [192][264] transposed
#pragma unroll
    for (int i = 0; i < 4; ++i)
#pragma unroll
      for (int j = 0; j < 6; ++j) {
        int ml = wr * 64 + i * 16 + lq * 4;
        int nl = wc * 96 + j * 16 + lr;
#pragma unroll
        for (int r = 0; r < 4; ++r)
          T[nl * 264 + ml + r] = f2b(acc[i][j][r]);
      }
    __syncthreads();
    const int h = n0 / HD;
    const int d0 = n0 - h * HD;
    for (int u = 0; u < 12; ++u) {
      int unit = u * 512 + tid;
      int nl = unit >> 5, c = unit & 31;
      int m = m0 + c * 8;
      if (m < MTOT) {
        int b = m / S_LEN, s = m - b * S_LEN;
        size_t row = (size_t)(b * NH + h) * HD + d0 + nl;
        *(s16x8*)&Vt[row * KPAD + s] = *(const s16x8*)&T[nl * 264 + c * 8];
      }
    }
  }
}

// ---------------------------------------------------------------------------
// FUSED attention v1 (best measured): per block one bh x 64 q-rows.
// 5 KV-tiles of 192 keys.  Per tile: 6 E-slots (T=Q*E^T -> TL bf16), 6 K-slots
// (S=Q*K^T), online softmax (P -> PL aliasing TL), 6 V-slots (O += P*V).
// Counted-vmcnt ring, swizzled LDS, setprio MFMA clusters.
// mode=1: read Q/K from ws, write O directly to d_out (single 480-blk launch,
// half derived from blockIdx, 2-bh-per-XCD-chunk mapping preserved).
// ---------------------------------------------------------------------------
#define FKV 192
#define FNT 5

#define WAITVM(N) { asm volatile("s_waitcnt vmcnt(" #N ")" ::: "memory"); \
  __builtin_amdgcn_sched_barrier(0); __builtin_amdgcn_s_barrier(); \
  __builtin_amdgcn_sched_barrier(0); }

#define LBAR { asm volatile("s_waitcnt lgkmcnt(0)" ::: "memory"); \
  __builtin_amdgcn_sched_barrier(0); __builtin_amdgcn_s_barrier(); \
  __builtin_amdgcn_sched_barrier(0); }

#define NOISSUE { }

#define STAGE_E(BUF, C, L0) { \
  _Pragma("unroll") for (int i_ = 0; i_ < 4; ++i_) { \
    int r_ = w * 32 + i_ * 8 + rl; \
    int rg_ = (L0) + r_; rg_ = rg_ < 0 ? 0 : (rg_ > LREL - 1 ? LREL - 1 : rg_); \
    load_lds16(Eb + (size_t)rg_ * HD + ((cs ^ (r_ & 7)) * 8) + (C) * 64, \
               (BUF) + (w * 32 + i_ * 8) * 64); } }

#define STAGE_K(BUF, C) { \
  _Pragma("unroll") for (int i_ = 0; i_ < 3; ++i_) { \
    int r_ = w * 24 + i_ * 8 + rl; \
    int rg_ = kv0 + r_; if (rg_ > S_LEN - 1) rg_ = S_LEN - 1; \
    load_lds16(Kp + (size_t)rg_ * DMODEL + ((cs ^ (r_ & 7)) * 8) + (C) * 64, \
               (BUF) + (w * 24 + i_ * 8) * 64); } }

#define STAGE_V(BUF, HF, SC) { \
  _Pragma("unroll") for (int i_ = 0; i_ < 3; ++i_) { \
    int r_ = w * 24 + i_ * 8 + rl; \
    load_lds16(Vb + (size_t)((HF) * 192 + r_) * KPAD + kv0 + (SC) * 64 + ((cs ^ (r_ & 7)) * 8), \
               (BUF) + (w * 24 + i_ * 8) * 64); } }

#define GSLOT_T(CUR, C, ISSUE, WVM) { ISSUE; WVM; \
  s16x8 a_[2][2], b_[2][4]; \
  _Pragma("unroll") for (int k_ = 0; k_ < 2; ++k_) { \
    _Pragma("unroll") for (int i_ = 0; i_ < 2; ++i_) \
      a_[i_][k_] = frag_swz(QL + (C) * 4096, wm * 32 + i_ * 16 + lr, k_, lq); \
    _Pragma("unroll") for (int j_ = 0; j_ < 4; ++j_) \
      b_[k_][j_] = frag_swz((CUR), wn * 64 + j_ * 16 + lr, k_, lq); } \
  __builtin_amdgcn_s_setprio(1); \
  _Pragma("unroll") for (int k_ = 0; k_ < 2; ++k_) \
    _Pragma("unroll") for (int i_ = 0; i_ < 2; ++i_) \
      _Pragma("unroll") for (int j_ = 0; j_ < 4; ++j_) \
        acc_t[i_][j_] = mfma_bf16(a_[i_][k_], b_[k_][j_], acc_t[i_][j_]); \
  __builtin_amdgcn_s_setprio(0); __builtin_amdgcn_s_barrier(); }

#define GSLOT_S(CUR, C, ISSUE, WVM) { ISSUE; WVM; \
  s16x8 a_[2][2], b_[2][3]; \
  _Pragma("unroll") for (int k_ = 0; k_ < 2; ++k_) { \
    _Pragma("unroll") for (int i_ = 0; i_ < 2; ++i_) \
      a_[i_][k_] = frag_swz(QL + (C) * 4096, wm * 32 + i_ * 16 + lr, k_, lq); \
    _Pragma("unroll") for (int j_ = 0; j_ < 3; ++j_) \
      b_[k_][j_] = frag_swz((CUR), wn * 48 + j_ * 16 + lr, k_, lq); } \
  __builtin_amdgcn_s_setprio(1); \
  _Pragma("unroll") for (int k_ = 0; k_ < 2; ++k_) \
    _Pragma("unroll") for (int i_ = 0; i_ < 2; ++i_) \
      _Pragma("unroll") for (int j_ = 0; j_ < 3; ++j_) \
        acc_s[i_][j_] = mfma_bf16(a_[i_][k_], b_[k_][j_], acc_s[i_][j_]); \
  __builtin_amdgcn_s_setprio(0); __builtin_amdgcn_s_barrier(); }

#define GSLOT_PV(CUR, SC, HF, ISSUE, WVM) { ISSUE; WVM; \
  s16x8 a_[2][2], b_[2][3]; \
  _Pragma("unroll") for (int k_ = 0; k_ < 2; ++k_) { \
    _Pragma("unroll") for (int i_ = 0; i_ < 2; ++i_) \
      a_[i_][k_] = frag_swz(TLP + (SC) * 4096, wm * 32 + i_ * 16 + lr, k_, lq); \
    _Pragma("unroll") for (int j_ = 0; j_ < 3; ++j_) \
      b_[k_][j_] = frag_swz((CUR), wn * 48 + j_ * 16 + lr, k_, lq); } \
  __builtin_amdgcn_s_setprio(1); \
  _Pragma("unroll") for (int k_ = 0; k_ < 2; ++k_) \
    _Pragma("unroll") for (int i_ = 0; i_ < 2; ++i_) \
      _Pragma("unroll") for (int j_ = 0; j_ < 3; ++j_) \
        acc_o[i_][(HF) * 3 + j_] = mfma_bf16(a_[i_][k_], b_[k_][j_], acc_o[i_][(HF) * 3 + j_]); \
  __builtin_amdgcn_s_setprio(0); __builtin_amdgcn_s_barrier(); }

__global__ __launch_bounds__(512, 1) void k_fused(const short* __restrict__ out16,
                                                  const short* __restrict__ Vt,
                                                  const short* __restrict__ Eb,
                                                  float* __restrict__ O,
                                                  const short* __restrict__ Qw,
                                                  const short* __restrict__ Kw,
                                                  int mode, int half) {
  __shared__ short smem[74752];          // 149.5 KB
  short* const QL  = smem;               // 6 chunks [64][64]   (24576)
  short* const B0  = smem + 24576;       // [256][64]           (16384)
  short* const B1  = smem + 40960;       // [256][64]           (16384)
  short* const TLP = smem + 57344;       // TL [64][256] / PL 3x[64][64] (16384)
  float* const pmax = (float*)(smem + 73728);   // [4][64]
  float* const psum = pmax + 256;               // [4][64]

  int f = blockIdx.x;                    // [0,240) or [0,480) in mode 1
  int hf = half;
  if (hf < 0) { hf = (f >= 240) ? 1 : 0; if (hf) f -= 240; }
  const int f2 = (f & 7) * 30 + (f >> 3);
  const int mt = f2 % 15, bhl = f2 / 15;
  const int bh = hf * 16 + bhl, b = bh >> 2, h = bh & 3;
  const int m0 = mt * 64;

  const int tid = threadIdx.x, w = tid >> 6, lane = tid & 63;
  const int lr = lane & 15, lq = lane >> 4;
  const int wm = w >> 2, wn = w & 3;     // 2m x 4n waves; wave = 32 rows x 48 cols
  const int rl = lane >> 3, cs = lane & 7;

  const short *Qp, *Kp;
  if (mode) {
    Qp = Qw + (size_t)b * S_LEN * DMODEL + h * HD;
    Kp = Kw + (size_t)b * S_LEN * DMODEL + h * HD;
  } else {
    Qp = out16 + (size_t)(b >> 1) * CHS + (size_t)(b & 1) * BSLAB + h * HD;
    Kp = Qp + KOFF;
  }
  const short* Vb = Vt + (size_t)bh * HD * KPAD;
  // O row address: mode ? O + (b*S+m)*DMODEL + h*HD + d : O + (bhl*S+m)*HD + d
  float* const Obase = mode ? (O + (size_t)b * S_LEN * DMODEL + h * HD)
                            : (O + (size_t)bhl * S_LEN * HD);
  const int ostride = mode ? DMODEL : HD;

  f32x4 acc_o[2][6];
  float Mst[2][4], Lst[2][4];
#pragma unroll
  for (int i = 0; i < 2; ++i) {
#pragma unroll
    for (int j = 0; j < 6; ++j) acc_o[i][j] = (f32x4){0.f, 0.f, 0.f, 0.f};
#pragma unroll
    for (int r = 0; r < 4; ++r) { Mst[i][r] = -1e30f; Lst[i][r] = 0.f; }
  }

  // prologue: QL (6 instrs/wave) + E0 of tile 0 into B0
#pragma unroll
  for (int i = 0; i < 6; ++i) {
    int rq = w * 8 + rl;
    int rg = m0 + rq; if (rg > S_LEN - 1) rg = S_LEN - 1;
    load_lds16(Qp + (size_t)rg * DMODEL + ((cs ^ (rq & 7)) * 8) + i * 64,
               QL + i * 4096 + (w * 8) * 64);
  }
  { const int l0p = 856 - m0; STAGE_E(B0, 0, l0p); }

  for (int t = 0; t < FNT; ++t) {
    const int kv0 = t * FKV;
    const int l0 = kv0 - m0 + 856;

    // ---- T phase: acc_t = Q * E^T  (cols l0..l0+255) ----
    f32x4 acc_t[2][4];
#pragma unroll
    for (int i = 0; i < 2; ++i)
#pragma unroll
      for (int j = 0; j < 4; ++j) acc_t[i][j] = (f32x4){0.f, 0.f, 0.f, 0.f};

    GSLOT_T(B0, 0, STAGE_E(B1, 1, l0), WAITVM(4));
    GSLOT_T(B1, 1, STAGE_E(B0, 2, l0), WAITVM(4));
    GSLOT_T(B0, 2, STAGE_E(B1, 3, l0), WAITVM(4));
    GSLOT_T(B1, 3, STAGE_E(B0, 4, l0), WAITVM(4));
    GSLOT_T(B0, 4, STAGE_E(B1, 5, l0), WAITVM(4));
    GSLOT_T(B1, 5, STAGE_K(B0, 0),     WAITVM(3));

    // TL write (bf16 [64][256])
#pragma unroll
    for (int i = 0; i < 2; ++i)
#pragma unroll
      for (int j = 0; j < 4; ++j)
#pragma unroll
        for (int r = 0; r < 4; ++r) {
          int row = wm * 32 + i * 16 + lq * 4 + r;
          int col = wn * 64 + j * 16 + lr;
          TLP[row * 256 + col] = f2b(acc_t[i][j][r]);
        }
    LBAR;

    // ---- S phase: acc_s = Q * K^T ----
    f32x4 acc_s[2][3];
#pragma unroll
    for (int i = 0; i < 2; ++i)
#pragma unroll
      for (int j = 0; j < 3; ++j) acc_s[i][j] = (f32x4){0.f, 0.f, 0.f, 0.f};

    GSLOT_S(B0, 0, STAGE_K(B1, 1), WAITVM(3));
    GSLOT_S(B1, 1, STAGE_K(B0, 2), WAITVM(3));
    GSLOT_S(B0, 2, STAGE_K(B1, 3), WAITVM(3));
    GSLOT_S(B1, 3, STAGE_K(B0, 4), WAITVM(3));
    GSLOT_S(B0, 4, STAGE_K(B1, 5), WAITVM(3));
    GSLOT_S(B1, 5, STAGE_V(B0, 0, 0), WAITVM(3));

    // ---- online softmax (V00 stays in flight; LDS-only barriers) ----
#pragma unroll
    for (int i = 0; i < 2; ++i)
#pragma unroll
      for (int j = 0; j < 3; ++j) {
        int jpl = wn * 48 + j * 16 + lr;
        int jp = kv0 + jpl;
#pragma unroll
        for (int r = 0; r < 4; ++r) {
          int row = wm * 32 + i * 16 + lq * 4 + r;
          float x = acc_s[i][j][r] + b2f(TLP[row * 256 + (jpl - row + 63)]);
          acc_s[i][j][r] = (jp < S_LEN) ? x : -1e30f;
        }
      }
    {
      float tm[2][4];
#pragma unroll
      for (int i = 0; i < 2; ++i)
#pragma unroll
        for (int r = 0; r < 4; ++r) {
          float v = fmaxf(fmaxf(acc_s[i][0][r], acc_s[i][1][r]), acc_s[i][2][r]);
#pragma unroll
          for (int o = 1; o < 16; o <<= 1) v = fmaxf(v, __shfl_xor(v, o));
          tm[i][r] = v;
        }
      if (lr == 0) {
#pragma unroll
        for (int i = 0; i < 2; ++i)
#pragma unroll
          for (int r = 0; r < 4; ++r)
            pmax[wn * 64 + wm * 32 + i * 16 + lq * 4 + r] = tm[i][r];
      }
    }
    LBAR;
    float fexp[2][4], ps[2][4];
#pragma unroll
    for (int i = 0; i < 2; ++i)
#pragma unroll
      for (int r = 0; r < 4; ++r) {
        int row = wm * 32 + i * 16 + lq * 4 + r;
        float M2 = fmaxf(fmaxf(pmax[row], pmax[64 + row]),
                         fmaxf(pmax[128 + row], pmax[192 + row]));
        M2 = fmaxf(M2, Mst[i][r]);
        fexp[i][r] = __expf(Mst[i][r] - M2);
        Mst[i][r] = M2;
      }
#pragma unroll
    for (int i = 0; i < 2; ++i)
#pragma unroll
      for (int r = 0; r < 4; ++r) {
        float s0 = 0.f;
#pragma unroll
        for (int j = 0; j < 3; ++j) {
          float p = __expf(acc_s[i][j][r] - Mst[i][r]);
          acc_s[i][j][r] = p;
          s0 += p;
        }
#pragma unroll
        for (int o = 1; o < 16; o <<= 1) s0 += __shfl_xor(s0, o);
        ps[i][r] = s0;
#pragma unroll
        for (int jj = 0; jj < 6; ++jj) acc_o[i][jj][r] *= fexp[i][r];
      }
    if (lr == 0) {
#pragma unroll
      for (int i = 0; i < 2; ++i)
#pragma unroll
        for (int r = 0; r < 4; ++r)
          psum[wn * 64 + wm * 32 + i * 16 + lq * 4 + r] = ps[i][r];
    }
    LBAR;
#pragma unroll
    for (int i = 0; i < 2; ++i)
#pragma unroll
      for (int r = 0; r < 4; ++r) {
        int row = wm * 32 + i * 16 + lq * 4 + r;
        float ts = psum[row] + psum[64 + row] + psum[128 + row] + psum[192 + row];
        Lst[i][r] = Lst[i][r] * fexp[i][r] + ts;
      }
    // P -> PL (bf16, swizzled A-layout; aliases TL, reads finished above)
#pragma unroll
    for (int i = 0; i < 2; ++i)
#pragma unroll
      for (int j = 0; j < 3; ++j) {
        int c192 = wn * 48 + j * 16 + lr;
        int sc = c192 >> 6, c64 = c192 & 63;
#pragma unroll
        for (int r = 0; r < 4; ++r) {
          int row = wm * 32 + i * 16 + lq * 4 + r;
          int byte = sc * 8192 + row * 128 + ((c64 * 2) ^ ((row & 7) * 16));
          *(short*)((char*)TLP + byte) = f2b(acc_s[i][j][r]);
        }
      }
    LBAR;

    // ---- PV phase: O += P * V ----
    GSLOT_PV(B0, 0, 0, STAGE_V(B1, 0, 1), WAITVM(3));
    GSLOT_PV(B1, 1, 0, STAGE_V(B0, 0, 2), WAITVM(3));
    GSLOT_PV(B0, 2, 0, STAGE_V(B1, 1, 0), WAITVM(3));
    GSLOT_PV(B1, 0, 1, STAGE_V(B0, 1, 1), WAITVM(3));
    GSLOT_PV(B0, 1, 1, STAGE_V(B1, 1, 2), WAITVM(3));
    if (t < FNT - 1) {
      GSLOT_PV(B1, 2, 1, STAGE_E(B0, 0, l0 + FKV), WAITVM(4));
    } else {
      GSLOT_PV(B1, 2, 1, NOISSUE, WAITVM(0));
    }
  }

  // ---- epilogue: O / L, store (scratch or direct d_out) ----
#pragma unroll
  for (int i = 0; i < 2; ++i)
#pragma unroll
    for (int r = 0; r < 4; ++r) {
      int m = m0 + wm * 32 + i * 16 + lq * 4 + r;
      if (m < S_LEN) {
        float rs = 1.0f / Lst[i][r];
#pragma unroll
        for (int jj = 0; jj < 6; ++jj) {
          int d = (jj / 3) * 192 + wn * 48 + (jj % 3) * 16 + lr;
          Obase[(size_t)m * ostride + d] = acc_o[i][jj][r] * rs;
        }
      }
    }
}

// O-scratch [16][920][384] f32 -> d_out (fallback mode only)
__global__ __launch_bounds__(256) void k_copy_o(const float* __restrict__ O,
                                                float* __restrict__ out, int b0) {
  int i = blockIdx.x * 256 + threadIdx.x;
  if (i >= 16 * S_LEN * HD / 4) return;
  const int per_bh = S_LEN * HD / 4;       // 88320
  int bhl = i / per_bh, rem = i - bhl * per_bh;
  int m = rem / (HD / 4), d4 = rem - m * (HD / 4);
  int b = b0 + (bhl >> 2), h = bhl & 3;
  float4 v = ((const float4*)O)[i];
  ((float4*)out)[((size_t)(b * S_LEN + m) * DMODEL + h * HD + d4 * 4) >> 2] = v;
}

// ---------------------------------------------------------------------------
extern "C" void kernel_launch(void* const* d_in, const int* in_sizes, int n_in,
                              void* d_out, int out_size, void* d_ws, size_t ws_size,
                              hipStream_t stream) {
  const float* hs = (const float*)d_in[0];
  const float* wq = (const float*)d_in[1];
  const float* wk = (const float*)d_in[2];
  const float* wv = (const float*)d_in[3];
  const float* de = (const float*)d_in[4];
  char* ws = (char*)d_ws;

  // layout: [Xb 22.6MB | also O-scratch][Wt 14.2MB][Eb 1.4MB][Vt 23.6MB]
  //         [+ direct mode: Qw 22.6MB | Kw 22.6MB]  (total 107 MB)
  short* Xb = (short*)(ws + 0);
  short* Wt = (short*)(ws + 22609920UL);
  short* Eb = (short*)(ws + 36765696UL);
  short* Vt = (short*)(ws + 36765696UL + EB_BYTES);
  float* Og = (float*)(ws + 0);          // aliases Xb (dead after qkv), fallback
  short* out16 = (short*)d_out;
  const int direct = (ws_size >= WS_DIRECT) ? 1 : 0;
  short* Qw = direct ? (short*)(ws + QW_OFF) : (short*)d_out;
  short* Kw = direct ? (short*)(ws + KW_OFF) : (short*)d_out;

  k_cast<<<(MTOT * DMODEL / 4 + 255) / 256, 256, 0, stream>>>(hs, Xb, MTOT * DMODEL / 4);
  k_prep_ev<<<(EB_N4 + PAD_N + 255) / 256, 256, 0, stream>>>(de, Eb, Vt);
  k_transpose_w<<<dim3(48, 48, 3), dim3(32, 8, 1), 0, stream>>>(wq, wk, wv, Wt);

  k_gemm_qkv<<<dim3(232, 1, 3), 512, 0, stream>>>(Xb, Wt, out16, Vt, Qw, Kw, direct);

  if (direct) {
    k_fused<<<dim3(480), 512, 0, stream>>>(out16, Vt, Eb, (float*)d_out,
                                           Qw, Kw, 1, -1);
  } else {
    for (int hf = 0; hf < 2; ++hf) {
      k_fused<<<dim3(240), 512, 0, stream>>>(out16, Vt, Eb, Og,
                                             nullptr, nullptr, 0, hf);
      k_copy_o<<<dim3(5520), 256, 0, stream>>>(Og, (float*)d_out, hf * 4);
    }
  }
}

// Round 12
// 413.634 us; speedup vs baseline: 1.0537x; 1.0059x over previous
//
#include <hip/hip_runtime.h>

#define S_LEN 920
#define DMODEL 1536
#define NH 4
#define HD 384
#define LREL 1839
#define BATCH 8
#define MTOT (BATCH * S_LEN)   // 7360
#define KPAD 960               // padded key-dim (Vt cols)
#define NBH (BATCH * NH)       // 32

// ---- Fallback layout: Q/K live inside d_out (shorts). Per 2-batch pair p,
// shorts [p*CHS,(p+1)*CHS) hold [Q(2p),K(2p),Q(2p+1),K(2p+1)]; fused half h
// reads batches 4h..4h+3, O goes to scratch, k_copy_o overwrites the slabs.
// ---- Direct mode (ws_size >= 107 MB): Q/K live in workspace, one fused
// launch writes d_out directly, no copies, no aliasing discipline.
#define CHS   5652480UL        // pair stride in shorts
#define BSLAB 2826240UL        // per-batch Q+K slab in shorts
#define KOFF  1413120UL        // K offset within batch slab (shorts)

#define EB_BYTES 1412352UL
#define VT_BYTES 23592960UL
#define QW_OFF   61771008UL    // byte offset of Q in ws (direct mode)
#define KW_OFF   84380928UL    // byte offset of K in ws (direct mode)
#define WS_DIRECT 106990848UL  // required ws_size for direct mode

typedef __attribute__((ext_vector_type(8))) short  s16x8;
typedef __attribute__((ext_vector_type(4))) short  s16x4;
typedef __attribute__((ext_vector_type(8))) __bf16 bf16x8;
typedef __attribute__((ext_vector_type(4))) float  f32x4;

__device__ __forceinline__ short f2b(float x) {
  unsigned u = __builtin_bit_cast(unsigned, x);
  unsigned r = (u + 0x7FFFu + ((u >> 16) & 1u)) >> 16;
  return (short)r;
}
__device__ __forceinline__ float b2f(short s) {
  unsigned u = ((unsigned)(unsigned short)s) << 16;
  return __builtin_bit_cast(float, u);
}

__device__ __forceinline__ void load_lds16(const short* g, short* lds) {
  __builtin_amdgcn_global_load_lds(
      (const __attribute__((address_space(1))) void*)g,
      (__attribute__((address_space(3))) void*)lds, 16, 0, 0);
}

__device__ __forceinline__ f32x4 mfma_bf16(s16x8 a, s16x8 b, f32x4 c) {
  return __builtin_amdgcn_mfma_f32_16x16x32_bf16(
      __builtin_bit_cast(bf16x8, a), __builtin_bit_cast(bf16x8, b), c, 0, 0, 0);
}

// swizzled ds_read of one MFMA fragment (row stride 128 B, XOR 16B-slot).
__device__ __forceinline__ s16x8 frag_swz(const short* base, int row, int kk, int lq) {
  int byte = (row << 7) + (kk << 6) + (lq << 4);
  byte ^= (row & 7) << 4;
  return *(const s16x8*)((const char*)base + byte);
}

// ---------------------------------------------------------------------------
// Pipelined 256x192 GEMM core (qkv) — proven.
// ---------------------------------------------------------------------------
template <int NT>
__device__ __forceinline__ void gemm_pipe(short* smem,
    const short* __restrict__ A, int ldA, int mClamp, int m0,
    const short* __restrict__ B, int ldB, int nClamp, int n0,
    f32x4 acc[4][6]) {
  short* const A0 = smem;
  short* const B0 = smem + 16384;
  short* const A1 = smem + 28672;
  short* const B1 = smem + 45056;

  const int tid = threadIdx.x, w = tid >> 6, lane = tid & 63;
  const int lr = lane & 15, lq = lane >> 4;
  const int wr = w >> 1, wc = w & 1;

  const short* pa[4]; int la[4];
  const short* pb[3]; int lb[3];
  {
    const int rl = lane >> 3, c = lane & 7;
#pragma unroll
    for (int i = 0; i < 4; ++i) {
      int r = w * 32 + i * 8 + rl;
      int ra = m0 + r; if (ra > mClamp) ra = mClamp;
      pa[i] = A + (size_t)ra * ldA + ((c ^ (r & 7)) * 8);
      la[i] = (w * 32 + i * 8) * 64;
    }
#pragma unroll
    for (int i = 0; i < 3; ++i) {
      int r = w * 24 + i * 8 + rl;
      int rb = n0 + r; if (rb > nClamp) rb = nClamp;
      pb[i] = B + (size_t)rb * ldB + ((c ^ (r & 7)) * 8);
      lb[i] = (w * 24 + i * 8) * 64;
    }
  }

#pragma unroll
  for (int i = 0; i < 4; ++i)
#pragma unroll
    for (int j = 0; j < 6; ++j) acc[i][j] = (f32x4){0.f, 0.f, 0.f, 0.f};

#pragma unroll
  for (int i = 0; i < 4; ++i) load_lds16(pa[i], A0 + la[i]);
#pragma unroll
  for (int i = 0; i < 3; ++i) load_lds16(pb[i], B0 + lb[i]);

  for (int kt = 0; kt < NT; ++kt) {
    short* const Ab = (kt & 1) ? A1 : A0;
    short* const Bb = (kt & 1) ? B1 : B0;
    short* const An = (kt & 1) ? A0 : A1;
    short* const Bn = (kt & 1) ? B0 : B1;

    if (kt + 1 < NT) {
      const int k0 = (kt + 1) * 64;
#pragma unroll
      for (int i = 0; i < 4; ++i) load_lds16(pa[i] + k0, An + la[i]);
#pragma unroll
      for (int i = 0; i < 3; ++i) load_lds16(pb[i] + k0, Bn + lb[i]);
      asm volatile("s_waitcnt vmcnt(7)" ::: "memory");
    } else {
      asm volatile("s_waitcnt vmcnt(0)" ::: "memory");
    }
    __builtin_amdgcn_sched_barrier(0);
    __builtin_amdgcn_s_barrier();
    __builtin_amdgcn_sched_barrier(0);

    s16x8 a[4], bb[3];
#pragma unroll
    for (int f = 0; f < 4; ++f) a[f] = frag_swz(Ab, wr * 64 + f * 16 + lr, 0, lq);
#pragma unroll
    for (int f = 0; f < 3; ++f) bb[f] = frag_swz(Bb, wc * 96 + f * 16 + lr, 0, lq);
    __builtin_amdgcn_s_barrier();
    __builtin_amdgcn_s_setprio(1);
#pragma unroll
    for (int i = 0; i < 4; ++i)
#pragma unroll
      for (int j = 0; j < 3; ++j) acc[i][j] = mfma_bf16(a[i], bb[j], acc[i][j]);
    __builtin_amdgcn_s_setprio(0);
    __builtin_amdgcn_s_barrier();
#pragma unroll
    for (int f = 0; f < 3; ++f) bb[f] = frag_swz(Bb, wc * 96 + (3 + f) * 16 + lr, 0, lq);
    __builtin_amdgcn_s_barrier();
    __builtin_amdgcn_s_setprio(1);
#pragma unroll
    for (int i = 0; i < 4; ++i)
#pragma unroll
      for (int j = 0; j < 3; ++j) acc[i][3 + j] = mfma_bf16(a[i], bb[j], acc[i][3 + j]);
    __builtin_amdgcn_s_setprio(0);
    __builtin_amdgcn_s_barrier();
#pragma unroll
    for (int f = 0; f < 4; ++f) a[f] = frag_swz(Ab, wr * 64 + f * 16 + lr, 1, lq);
#pragma unroll
    for (int f = 0; f < 3; ++f) bb[f] = frag_swz(Bb, wc * 96 + f * 16 + lr, 1, lq);
    __builtin_amdgcn_s_barrier();
    __builtin_amdgcn_s_setprio(1);
#pragma unroll
    for (int i = 0; i < 4; ++i)
#pragma unroll
      for (int j = 0; j < 3; ++j) acc[i][j] = mfma_bf16(a[i], bb[j], acc[i][j]);
    __builtin_amdgcn_s_setprio(0);
    __builtin_amdgcn_s_barrier();
#pragma unroll
    for (int f = 0; f < 3; ++f) bb[f] = frag_swz(Bb, wc * 96 + (3 + f) * 16 + lr, 1, lq);
    __builtin_amdgcn_s_barrier();
    __builtin_amdgcn_s_setprio(1);
#pragma unroll
    for (int i = 0; i < 4; ++i)
#pragma unroll
      for (int j = 0; j < 3; ++j) acc[i][3 + j] = mfma_bf16(a[i], bb[j], acc[i][3 + j]);
    __builtin_amdgcn_s_setprio(0);
    __builtin_amdgcn_s_barrier();
  }
}

// ---------------------------------------------------------------------------
__global__ void k_cast(const float* __restrict__ X, short* __restrict__ O, int n4) {
  int i = blockIdx.x * blockDim.x + threadIdx.x;
  if (i >= n4) return;
  float4 v = ((const float4*)X)[i];
  s16x4 o = {f2b(v.x), f2b(v.y), f2b(v.z), f2b(v.w)};
  *(s16x4*)&O[(size_t)i * 4] = o;
}

// merged: cast distance_embedding -> Eb  AND  zero Vt pad columns (disjoint).
#define EB_N4   (LREL * HD / 4)                   // 176544
#define PAD_N   (NBH * HD * (KPAD - S_LEN))       // 491520
__global__ void k_prep_ev(const float* __restrict__ de, short* __restrict__ Eb,
                          short* __restrict__ Vt) {
  int i = blockIdx.x * blockDim.x + threadIdx.x;
  if (i < EB_N4) {
    float4 v = ((const float4*)de)[i];
    s16x4 o = {f2b(v.x), f2b(v.y), f2b(v.z), f2b(v.w)};
    *(s16x4*)&Eb[(size_t)i * 4] = o;
  } else {
    int idx = i - EB_N4;
    if (idx < PAD_N) {
      int bhd = idx / (KPAD - S_LEN);
      int s = S_LEN + idx - bhd * (KPAD - S_LEN);
      Vt[(size_t)bhd * KPAD + s] = 0;
    }
  }
}

__global__ void k_transpose_w(const float* __restrict__ W0, const float* __restrict__ W1,
                              const float* __restrict__ W2, short* __restrict__ Wt) {
  const float* W = (blockIdx.z == 0) ? W0 : ((blockIdx.z == 1) ? W1 : W2);
  short* O = Wt + (size_t)blockIdx.z * DMODEL * DMODEL;
  __shared__ float t[32][33];
  int tx = threadIdx.x, ty = threadIdx.y;
  int n0 = blockIdx.x * 32, k0 = blockIdx.y * 32;
#pragma unroll
  for (int i = 0; i < 4; ++i)
    t[ty + i * 8][tx] = W[(size_t)(k0 + ty + i * 8) * DMODEL + n0 + tx];
  __syncthreads();
#pragma unroll
  for (int i = 0; i < 4; ++i)
    O[(size_t)(n0 + ty + i * 8) * DMODEL + k0 + tx] = f2b(t[tx][ty + i * 8]);
}

// ---------------------------------------------------------------------------
// QKV: 256x192 tile pipeline.  Grid (232,1,3), 1 block/CU.  Chunked XCD
// swizzle (FETCH 115 MB; linear n=t&7 variant measured 258 MB — refuted).
// mode=1: Q/K go to workspace (plain [m][1536] layout); mode=0: d_out slabs.
// ---------------------------------------------------------------------------
#define QKV_NT (DMODEL / 64)   // 24 K-tiles

__global__ __launch_bounds__(512, 2) void k_gemm_qkv(const short* __restrict__ Xb,
                                                     const short* __restrict__ Wt,
                                                     short* __restrict__ out16,
                                                     short* __restrict__ Vt,
                                                     short* __restrict__ Qw,
                                                     short* __restrict__ Kw,
                                                     int mode) {
  __shared__ short smem[57344];
  const int z = blockIdx.z;
  const int t = blockIdx.x;
  const int t2 = (t & 7) * 29 + (t >> 3);
  const int m0 = (t2 >> 3) * 256;
  const int n0 = (t2 & 7) * 192;

  const int tid = threadIdx.x, w = tid >> 6, lane = tid & 63;
  const int lr = lane & 15, lq = lane >> 4;
  const int wr = w >> 1, wc = w & 1;

  f32x4 acc[4][6];
  gemm_pipe<QKV_NT>(smem, Xb, DMODEL, MTOT - 1, m0,
                    Wt + (size_t)z * DMODEL * DMODEL, DMODEL, DMODEL - 1, n0, acc);

  __syncthreads();
  const float inv = 0.05103103630798287f;       // 1/sqrt(384)
  if (z != 2) {
    short* T = smem;                            // [256][200]
#pragma unroll
    for (int i = 0; i < 4; ++i)
#pragma unroll
      for (int j = 0; j < 6; ++j) {
        int ml = wr * 64 + i * 16 + lq * 4;
        int nl = wc * 96 + j * 16 + lr;
#pragma unroll
        for (int r = 0; r < 4; ++r) {
          float v = acc[i][j][r];
          T[(ml + r) * 200 + nl] = f2b(z == 0 ? v * inv : v);
        }
      }
    __syncthreads();
    for (int u = 0; u < 12; ++u) {
      int unit = u * 512 + tid;
      int ml = unit / 24, c = unit - ml * 24;
      int m = m0 + ml;
      if (m < MTOT) {
        short* dst;
        if (mode) {
          dst = (z == 0 ? Qw : Kw) + (size_t)m * DMODEL + n0 + c * 8;
        } else {
          int b = m / S_LEN, s = m - b * S_LEN;
          dst = out16 + (size_t)(b >> 1) * CHS + (size_t)(b & 1) * BSLAB +
                (z == 1 ? KOFF : 0UL) + (size_t)s * DMODEL + n0 + c * 8;
        }
        *(s16x8*)dst = *(const s16x8*)&T[ml * 200 + c * 8];
      }
    }
  } else {
    short* T = smem;                            // [192][264] transposed
#pragma unroll
    for (int i = 0; i < 4; ++i)
#pragma unroll
      for (int j = 0; j < 6; ++j) {
        int ml = wr * 64 + i * 16 + lq * 4;
        int nl = wc * 96 + j * 16 + lr;
#pragma unroll
        for (int r = 0; r < 4; ++r)
          T[nl * 264 + ml + r] = f2b(acc[i][j][r]);
      }
    __syncthreads();
    const int h = n0 / HD;
    const int d0 = n0 - h * HD;
    for (int u = 0; u < 12; ++u) {
      int unit = u * 512 + tid;
      int nl = unit >> 5, c = unit & 31;
      int m = m0 + c * 8;
      if (m < MTOT) {
        int b = m / S_LEN, s = m - b * S_LEN;
        size_t row = (size_t)(b * NH + h) * HD + d0 + nl;
        *(s16x8*)&Vt[row * KPAD + s] = *(const s16x8*)&T[nl * 264 + c * 8];
      }
    }
  }
}

// ---------------------------------------------------------------------------
// FUSED attention v1 (best measured): per block one bh x 64 q-rows.
// 5 KV-tiles of 192 keys.  Per tile: 6 E-slots (T=Q*E^T -> TL bf16), 6 K-slots
// (S=Q*K^T), online softmax (P -> PL aliasing TL), 6 V-slots (O += P*V).
// Counted-vmcnt ring, swizzled LDS, setprio MFMA clusters.
// mode=1: read Q/K from ws, write O directly to d_out (single 480-blk launch,
// half derived from blockIdx, 2-bh-per-XCD-chunk mapping preserved).
// ---------------------------------------------------------------------------
#define FKV 192
#define FNT 5

#define WAITVM(N) { asm volatile("s_waitcnt vmcnt(" #N ")" ::: "memory"); \
  __builtin_amdgcn_sched_barrier(0); __builtin_amdgcn_s_barrier(); \
  __builtin_amdgcn_sched_barrier(0); }

#define LBAR { asm volatile("s_waitcnt lgkmcnt(0)" ::: "memory"); \
  __builtin_amdgcn_sched_barrier(0); __builtin_amdgcn_s_barrier(); \
  __builtin_amdgcn_sched_barrier(0); }

#define NOISSUE { }

#define STAGE_E(BUF, C, L0) { \
  _Pragma("unroll") for (int i_ = 0; i_ < 4; ++i_) { \
    int r_ = w * 32 + i_ * 8 + rl; \
    int rg_ = (L0) + r_; rg_ = rg_ < 0 ? 0 : (rg_ > LREL - 1 ? LREL - 1 : rg_); \
    load_lds16(Eb + (size_t)rg_ * HD + ((cs ^ (r_ & 7)) * 8) + (C) * 64, \
               (BUF) + (w * 32 + i_ * 8) * 64); } }

#define STAGE_K(BUF, C) { \
  _Pragma("unroll") for (int i_ = 0; i_ < 3; ++i_) { \
    int r_ = w * 24 + i_ * 8 + rl; \
    int rg_ = kv0 + r_; if (rg_ > S_LEN - 1) rg_ = S_LEN - 1; \
    load_lds16(Kp + (size_t)rg_ * DMODEL + ((cs ^ (r_ & 7)) * 8) + (C) * 64, \
               (BUF) + (w * 24 + i_ * 8) * 64); } }

#define STAGE_V(BUF, HF, SC) { \
  _Pragma("unroll") for (int i_ = 0; i_ < 3; ++i_) { \
    int r_ = w * 24 + i_ * 8 + rl; \
    load_lds16(Vb + (size_t)((HF) * 192 + r_) * KPAD + kv0 + (SC) * 64 + ((cs ^ (r_ & 7)) * 8), \
               (BUF) + (w * 24 + i_ * 8) * 64); } }

#define GSLOT_T(CUR, C, ISSUE, WVM) { ISSUE; WVM; \
  s16x8 a_[2][2], b_[2][4]; \
  _Pragma("unroll") for (int k_ = 0; k_ < 2; ++k_) { \
    _Pragma("unroll") for (int i_ = 0; i_ < 2; ++i_) \
      a_[i_][k_] = frag_swz(QL + (C) * 4096, wm * 32 + i_ * 16 + lr, k_, lq); \
    _Pragma("unroll") for (int j_ = 0; j_ < 4; ++j_) \
      b_[k_][j_] = frag_swz((CUR), wn * 64 + j_ * 16 + lr, k_, lq); } \
  __builtin_amdgcn_s_setprio(1); \
  _Pragma("unroll") for (int k_ = 0; k_ < 2; ++k_) \
    _Pragma("unroll") for (int i_ = 0; i_ < 2; ++i_) \
      _Pragma("unroll") for (int j_ = 0; j_ < 4; ++j_) \
        acc_t[i_][j_] = mfma_bf16(a_[i_][k_], b_[k_][j_], acc_t[i_][j_]); \
  __builtin_amdgcn_s_setprio(0); __builtin_amdgcn_s_barrier(); }

#define GSLOT_S(CUR, C, ISSUE, WVM) { ISSUE; WVM; \
  s16x8 a_[2][2], b_[2][3]; \
  _Pragma("unroll") for (int k_ = 0; k_ < 2; ++k_) { \
    _Pragma("unroll") for (int i_ = 0; i_ < 2; ++i_) \
      a_[i_][k_] = frag_swz(QL + (C) * 4096, wm * 32 + i_ * 16 + lr, k_, lq); \
    _Pragma("unroll") for (int j_ = 0; j_ < 3; ++j_) \
      b_[k_][j_] = frag_swz((CUR), wn * 48 + j_ * 16 + lr, k_, lq); } \
  __builtin_amdgcn_s_setprio(1); \
  _Pragma("unroll") for (int k_ = 0; k_ < 2; ++k_) \
    _Pragma("unroll") for (int i_ = 0; i_ < 2; ++i_) \
      _Pragma("unroll") for (int j_ = 0; j_ < 3; ++j_) \
        acc_s[i_][j_] = mfma_bf16(a_[i_][k_], b_[k_][j_], acc_s[i_][j_]); \
  __builtin_amdgcn_s_setprio(0); __builtin_amdgcn_s_barrier(); }

#define GSLOT_PV(CUR, SC, HF, ISSUE, WVM) { ISSUE; WVM; \
  s16x8 a_[2][2], b_[2][3]; \
  _Pragma("unroll") for (int k_ = 0; k_ < 2; ++k_) { \
    _Pragma("unroll") for (int i_ = 0; i_ < 2; ++i_) \
      a_[i_][k_] = frag_swz(TLP + (SC) * 4096, wm * 32 + i_ * 16 + lr, k_, lq); \
    _Pragma("unroll") for (int j_ = 0; j_ < 3; ++j_) \
      b_[k_][j_] = frag_swz((CUR), wn * 48 + j_ * 16 + lr, k_, lq); } \
  __builtin_amdgcn_s_setprio(1); \
  _Pragma("unroll") for (int k_ = 0; k_ < 2; ++k_) \
    _Pragma("unroll") for (int i_ = 0; i_ < 2; ++i_) \
      _Pragma("unroll") for (int j_ = 0; j_ < 3; ++j_) \
        acc_o[i_][(HF) * 3 + j_] = mfma_bf16(a_[i_][k_], b_[k_][j_], acc_o[i_][(HF) * 3 + j_]); \
  __builtin_amdgcn_s_setprio(0); __builtin_amdgcn_s_barrier(); }

__global__ __launch_bounds__(512, 1) void k_fused(const short* __restrict__ out16,
                                                  const short* __restrict__ Vt,
                                                  const short* __restrict__ Eb,
                                                  float* __restrict__ O,
                                                  const short* __restrict__ Qw,
                                                  const short* __restrict__ Kw,
                                                  int mode, int half) {
  __shared__ short smem[74752];          // 149.5 KB
  short* const QL  = smem;               // 6 chunks [64][64]   (24576)
  short* const B0  = smem + 24576;       // [256][64]           (16384)
  short* const B1  = smem + 40960;       // [256][64]           (16384)
  short* const TLP = smem + 57344;       // TL [64][256] / PL 3x[64][64] (16384)
  float* const pmax = (float*)(smem + 73728);   // [4][64]
  float* const psum = pmax + 256;               // [4][64]

  int f = blockIdx.x;                    // [0,240) or [0,480) in mode 1
  int hf = half;
  if (hf < 0) { hf = (f >= 240) ? 1 : 0; if (hf) f -= 240; }
  const int f2 = (f & 7) * 30 + (f >> 3);
  const int mt = f2 % 15, bhl = f2 / 15;
  const int bh = hf * 16 + bhl, b = bh >> 2, h = bh & 3;
  const int m0 = mt * 64;

  const int tid = threadIdx.x, w = tid >> 6, lane = tid & 63;
  const int lr = lane & 15, lq = lane >> 4;
  const int wm = w >> 2, wn = w & 3;     // 2m x 4n waves; wave = 32 rows x 48 cols
  const int rl = lane >> 3, cs = lane & 7;

  const short *Qp, *Kp;
  if (mode) {
    Qp = Qw + (size_t)b * S_LEN * DMODEL + h * HD;
    Kp = Kw + (size_t)b * S_LEN * DMODEL + h * HD;
  } else {
    Qp = out16 + (size_t)(b >> 1) * CHS + (size_t)(b & 1) * BSLAB + h * HD;
    Kp = Qp + KOFF;
  }
  const short* Vb = Vt + (size_t)bh * HD * KPAD;
  // O row address: mode ? O + (b*S+m)*DMODEL + h*HD + d : O + (bhl*S+m)*HD + d
  float* const Obase = mode ? (O + (size_t)b * S_LEN * DMODEL + h * HD)
                            : (O + (size_t)bhl * S_LEN * HD);
  const int ostride = mode ? DMODEL : HD;

  f32x4 acc_o[2][6];
  float Mst[2][4], Lst[2][4];
#pragma unroll
  for (int i = 0; i < 2; ++i) {
#pragma unroll
    for (int j = 0; j < 6; ++j) acc_o[i][j] = (f32x4){0.f, 0.f, 0.f, 0.f};
#pragma unroll
    for (int r = 0; r < 4; ++r) { Mst[i][r] = -1e30f; Lst[i][r] = 0.f; }
  }

  // prologue: QL (6 instrs/wave) + E0 of tile 0 into B0
#pragma unroll
  for (int i = 0; i < 6; ++i) {
    int rq = w * 8 + rl;
    int rg = m0 + rq; if (rg > S_LEN - 1) rg = S_LEN - 1;
    load_lds16(Qp + (size_t)rg * DMODEL + ((cs ^ (rq & 7)) * 8) + i * 64,
               QL + i * 4096 + (w * 8) * 64);
  }
  { const int l0p = 856 - m0; STAGE_E(B0, 0, l0p); }

  for (int t = 0; t < FNT; ++t) {
    const int kv0 = t * FKV;
    const int l0 = kv0 - m0 + 856;

    // ---- T phase: acc_t = Q * E^T  (cols l0..l0+255) ----
    f32x4 acc_t[2][4];
#pragma unroll
    for (int i = 0; i < 2; ++i)
#pragma unroll
      for (int j = 0; j < 4; ++j) acc_t[i][j] = (f32x4){0.f, 0.f, 0.f, 0.f};

    GSLOT_T(B0, 0, STAGE_E(B1, 1, l0), WAITVM(4));
    GSLOT_T(B1, 1, STAGE_E(B0, 2, l0), WAITVM(4));
    GSLOT_T(B0, 2, STAGE_E(B1, 3, l0), WAITVM(4));
    GSLOT_T(B1, 3, STAGE_E(B0, 4, l0), WAITVM(4));
    GSLOT_T(B0, 4, STAGE_E(B1, 5, l0), WAITVM(4));
    GSLOT_T(B1, 5, STAGE_K(B0, 0),     WAITVM(3));

    // TL write (bf16 [64][256])
#pragma unroll
    for (int i = 0; i < 2; ++i)
#pragma unroll
      for (int j = 0; j < 4; ++j)
#pragma unroll
        for (int r = 0; r < 4; ++r) {
          int row = wm * 32 + i * 16 + lq * 4 + r;
          int col = wn * 64 + j * 16 + lr;
          TLP[row * 256 + col] = f2b(acc_t[i][j][r]);
        }
    LBAR;

    // ---- S phase: acc_s = Q * K^T ----
    f32x4 acc_s[2][3];
#pragma unroll
    for (int i = 0; i < 2; ++i)
#pragma unroll
      for (int j = 0; j < 3; ++j) acc_s[i][j] = (f32x4){0.f, 0.f, 0.f, 0.f};

    GSLOT_S(B0, 0, STAGE_K(B1, 1), WAITVM(3));
    GSLOT_S(B1, 1, STAGE_K(B0, 2), WAITVM(3));
    GSLOT_S(B0, 2, STAGE_K(B1, 3), WAITVM(3));
    GSLOT_S(B1, 3, STAGE_K(B0, 4), WAITVM(3));
    GSLOT_S(B0, 4, STAGE_K(B1, 5), WAITVM(3));
    GSLOT_S(B1, 5, STAGE_V(B0, 0, 0), WAITVM(3));

    // ---- online softmax (V00 stays in flight; LDS-only barriers) ----
#pragma unroll
    for (int i = 0; i < 2; ++i)
#pragma unroll
      for (int j = 0; j < 3; ++j) {
        int jpl = wn * 48 + j * 16 + lr;
        int jp = kv0 + jpl;
#pragma unroll
        for (int r = 0; r < 4; ++r) {
          int row = wm * 32 + i * 16 + lq * 4 + r;
          float x = acc_s[i][j][r] + b2f(TLP[row * 256 + (jpl - row + 63)]);
          acc_s[i][j][r] = (jp < S_LEN) ? x : -1e30f;
        }
      }
    {
      float tm[2][4];
#pragma unroll
      for (int i = 0; i < 2; ++i)
#pragma unroll
        for (int r = 0; r < 4; ++r) {
          float v = fmaxf(fmaxf(acc_s[i][0][r], acc_s[i][1][r]), acc_s[i][2][r]);
#pragma unroll
          for (int o = 1; o < 16; o <<= 1) v = fmaxf(v, __shfl_xor(v, o));
          tm[i][r] = v;
        }
      if (lr == 0) {
#pragma unroll
        for (int i = 0; i < 2; ++i)
#pragma unroll
          for (int r = 0; r < 4; ++r)
            pmax[wn * 64 + wm * 32 + i * 16 + lq * 4 + r] = tm[i][r];
      }
    }
    LBAR;
    float fexp[2][4], ps[2][4];
#pragma unroll
    for (int i = 0; i < 2; ++i)
#pragma unroll
      for (int r = 0; r < 4; ++r) {
        int row = wm * 32 + i * 16 + lq * 4 + r;
        float M2 = fmaxf(fmaxf(pmax[row], pmax[64 + row]),
                         fmaxf(pmax[128 + row], pmax[192 + row]));
        M2 = fmaxf(M2, Mst[i][r]);
        fexp[i][r] = __expf(Mst[i][r] - M2);
        Mst[i][r] = M2;
      }
#pragma unroll
    for (int i = 0; i < 2; ++i)
#pragma unroll
      for (int r = 0; r < 4; ++r) {
        float s0 = 0.f;
#pragma unroll
        for (int j = 0; j < 3; ++j) {
          float p = __expf(acc_s[i][j][r] - Mst[i][r]);
          acc_s[i][j][r] = p;
          s0 += p;
        }
#pragma unroll
        for (int o = 1; o < 16; o <<= 1) s0 += __shfl_xor(s0, o);
        ps[i][r] = s0;
#pragma unroll
        for (int jj = 0; jj < 6; ++jj) acc_o[i][jj][r] *= fexp[i][r];
      }
    if (lr == 0) {
#pragma unroll
      for (int i = 0; i < 2; ++i)
#pragma unroll
        for (int r = 0; r < 4; ++r)
          psum[wn * 64 + wm * 32 + i * 16 + lq * 4 + r] = ps[i][r];
    }
    LBAR;
#pragma unroll
    for (int i = 0; i < 2; ++i)
#pragma unroll
      for (int r = 0; r < 4; ++r) {
        int row = wm * 32 + i * 16 + lq * 4 + r;
        float ts = psum[row] + psum[64 + row] + psum[128 + row] + psum[192 + row];
        Lst[i][r] = Lst[i][r] * fexp[i][r] + ts;
      }
    // P -> PL (bf16, swizzled A-layout; aliases TL, reads finished above)
#pragma unroll
    for (int i = 0; i < 2; ++i)
#pragma unroll
      for (int j = 0; j < 3; ++j) {
        int c192 = wn * 48 + j * 16 + lr;
        int sc = c192 >> 6, c64 = c192 & 63;
#pragma unroll
        for (int r = 0; r < 4; ++r) {
          int row = wm * 32 + i * 16 + lq * 4 + r;
          int byte = sc * 8192 + row * 128 + ((c64 * 2) ^ ((row & 7) * 16));
          *(short*)((char*)TLP + byte) = f2b(acc_s[i][j][r]);
        }
      }
    LBAR;

    // ---- PV phase: O += P * V ----
    GSLOT_PV(B0, 0, 0, STAGE_V(B1, 0, 1), WAITVM(3));
    GSLOT_PV(B1, 1, 0, STAGE_V(B0, 0, 2), WAITVM(3));
    GSLOT_PV(B0, 2, 0, STAGE_V(B1, 1, 0), WAITVM(3));
    GSLOT_PV(B1, 0, 1, STAGE_V(B0, 1, 1), WAITVM(3));
    GSLOT_PV(B0, 1, 1, STAGE_V(B1, 1, 2), WAITVM(3));
    if (t < FNT - 1) {
      GSLOT_PV(B1, 2, 1, STAGE_E(B0, 0, l0 + FKV), WAITVM(4));
    } else {
      GSLOT_PV(B1, 2, 1, NOISSUE, WAITVM(0));
    }
  }

  // ---- epilogue: O / L, store (scratch or direct d_out) ----
#pragma unroll
  for (int i = 0; i < 2; ++i)
#pragma unroll
    for (int r = 0; r < 4; ++r) {
      int m = m0 + wm * 32 + i * 16 + lq * 4 + r;
      if (m < S_LEN) {
        float rs = 1.0f / Lst[i][r];
#pragma unroll
        for (int jj = 0; jj < 6; ++jj) {
          int d = (jj / 3) * 192 + wn * 48 + (jj % 3) * 16 + lr;
          Obase[(size_t)m * ostride + d] = acc_o[i][jj][r] * rs;
        }
      }
    }
}

// O-scratch [16][920][384] f32 -> d_out (fallback mode only)
__global__ __launch_bounds__(256) void k_copy_o(const float* __restrict__ O,
                                                float* __restrict__ out, int b0) {
  int i = blockIdx.x * 256 + threadIdx.x;
  if (i >= 16 * S_LEN * HD / 4) return;
  const int per_bh = S_LEN * HD / 4;       // 88320
  int bhl = i / per_bh, rem = i - bhl * per_bh;
  int m = rem / (HD / 4), d4 = rem - m * (HD / 4);
  int b = b0 + (bhl >> 2), h = bhl & 3;
  float4 v = ((const float4*)O)[i];
  ((float4*)out)[((size_t)(b * S_LEN + m) * DMODEL + h * HD + d4 * 4) >> 2] = v;
}

// ---------------------------------------------------------------------------
extern "C" void kernel_launch(void* const* d_in, const int* in_sizes, int n_in,
                              void* d_out, int out_size, void* d_ws, size_t ws_size,
                              hipStream_t stream) {
  const float* hs = (const float*)d_in[0];
  const float* wq = (const float*)d_in[1];
  const float* wk = (const float*)d_in[2];
  const float* wv = (const float*)d_in[3];
  const float* de = (const float*)d_in[4];
  char* ws = (char*)d_ws;

  // layout: [Xb 22.6MB | also O-scratch][Wt 14.2MB][Eb 1.4MB][Vt 23.6MB]
  //         [+ direct mode: Qw 22.6MB | Kw 22.6MB]  (total 107 MB)
  short* Xb = (short*)(ws + 0);
  short* Wt = (short*)(ws + 22609920UL);
  short* Eb = (short*)(ws + 36765696UL);
  short* Vt = (short*)(ws + 36765696UL + EB_BYTES);
  float* Og = (float*)(ws + 0);          // aliases Xb (dead after qkv), fallback
  short* out16 = (short*)d_out;
  const int direct = (ws_size >= WS_DIRECT) ? 1 : 0;
  short* Qw = direct ? (short*)(ws + QW_OFF) : (short*)d_out;
  short* Kw = direct ? (short*)(ws + KW_OFF) : (short*)d_out;

  k_cast<<<(MTOT * DMODEL / 4 + 255) / 256, 256, 0, stream>>>(hs, Xb, MTOT * DMODEL / 4);
  k_prep_ev<<<(EB_N4 + PAD_N + 255) / 256, 256, 0, stream>>>(de, Eb, Vt);
  k_transpose_w<<<dim3(48, 48, 3), dim3(32, 8, 1), 0, stream>>>(wq, wk, wv, Wt);

  k_gemm_qkv<<<dim3(232, 1, 3), 512, 0, stream>>>(Xb, Wt, out16, Vt, Qw, Kw, direct);

  if (direct) {
    k_fused<<<dim3(480), 512, 0, stream>>>(out16, Vt, Eb, (float*)d_out,
                                           Qw, Kw, 1, -1);
  } else {
    for (int hf = 0; hf < 2; ++hf) {
      k_fused<<<dim3(240), 512, 0, stream>>>(out16, Vt, Eb, Og,
                                             nullptr, nullptr, 0, hf);
      k_copy_o<<<dim3(5520), 256, 0, stream>>>(Og, (float*)d_out, hf * 4);
    }
  }
}